// Round 13
// baseline (733.024 us; speedup 1.0000x reference)
//
#include <hip/hip_runtime.h>
#include <stdint.h>

// Problem constants
#define T_TOK 4096   // B*S
#define HIDD  2048
#define NH    16
#define DNN   128
#define DRR   64
#define DVV   128
#define LAT   512
#define DQK   576    // LAT + DR
#define SEQ   2048
#define NB    2
#define KSTR  592    // padded keff row stride (ushorts) = 74 chunks of 16B
#define QCKV  3712   // merged q(3072) + ckv(640) row stride

typedef __attribute__((__ext_vector_type__(8))) short short8;
typedef __attribute__((__ext_vector_type__(4))) short short4v;
typedef __attribute__((__ext_vector_type__(4))) float f32x4;

// PV MFMA: D(16x16) = A(16rows x K16) * B(K16 x 16cols) + C, bf16 in f32 out.
#if __has_builtin(__builtin_amdgcn_mfma_f32_16x16x16_bf16)
#define MFMA16(a, b, c) __builtin_amdgcn_mfma_f32_16x16x16_bf16(a, b, c, 0, 0, 0)
#elif __has_builtin(__builtin_amdgcn_mfma_f32_16x16x16bf16_1k)
#define MFMA16(a, b, c) __builtin_amdgcn_mfma_f32_16x16x16bf16_1k(a, b, c, 0, 0, 0)
#else
__device__ __forceinline__ f32x4 mfma16_asm(short4v a, short4v b, f32x4 c) {
  asm volatile("v_mfma_f32_16x16x16_bf16 %0, %1, %2, %0" : "+v"(c) : "v"(a), "v"(b));
  return c;
}
#define MFMA16(a, b, c) mfma16_asm(a, b, c)
#endif

__device__ __forceinline__ float bf2f(ushort u) {
  union { uint32_t i; float f; } v; v.i = ((uint32_t)u) << 16; return v.f;
}
__device__ __forceinline__ ushort f2bf(float f) {
  union { float f; uint32_t i; } v; v.f = f;
  uint32_t r = v.i + 0x7FFF + ((v.i >> 16) & 1);
  return (ushort)(r >> 16);
}

__device__ __forceinline__ void gld_lds16(const void* g, void* l) {
  __builtin_amdgcn_global_load_lds((const __attribute__((address_space(1))) void*)g,
                                   (__attribute__((address_space(3))) void*)l, 16, 0, 0);
}

// ---------------- cast kernels ----------------
__global__ void cast4(const float* __restrict__ in, ushort* __restrict__ out, int n4) {
  int i = blockIdx.x * blockDim.x + threadIdx.x;
  if (i >= n4) return;
  float4 v = ((const float4*)in)[i];
  ushort4 o; o.x = f2bf(v.x); o.y = f2bf(v.y); o.z = f2bf(v.z); o.w = f2bf(v.w);
  ((ushort4*)out)[i] = o;
}

// kv_a_proj_w (576x2048) -> padded (640x2048) bf16, pad rows zero
__global__ void cast_pad_kv(const float* __restrict__ in, ushort* __restrict__ out) {
  int i = blockIdx.x * 256 + threadIdx.x;     // over 640*2048/4
  int row = (i * 4) >> 11;
  ushort4 o;
  if (row < 576) {
    float4 v = ((const float4*)in)[i];
    o.x = f2bf(v.x); o.y = f2bf(v.y); o.z = f2bf(v.z); o.w = f2bf(v.w);
  } else { o.x = 0; o.y = 0; o.z = 0; o.w = 0; }
  ((ushort4*)out)[i] = o;
}

// wuk_t[h][l][d] = W_UK_T[h][d][l]
__global__ void cast_wuk(const float* __restrict__ in, ushort* __restrict__ out) {
  int o = blockIdx.x * 256 + threadIdx.x;   // 16*512*128
  int d = o & 127, l = (o >> 7) & 511, h = o >> 16;
  out[o] = f2bf(in[((size_t)(h * 128 + d)) * 512 + l]);
}
// wuv_t[h][v][l] = W_UV[h][l][v]
__global__ void cast_wuv(const float* __restrict__ in, ushort* __restrict__ out) {
  int o = blockIdx.x * 256 + threadIdx.x;   // 16*128*512
  int l = o & 511, v = (o >> 9) & 127, h = o >> 16;
  out[o] = f2bf(in[((size_t)(h * 512 + l)) * 128 + v]);
}

// ---------------- GEMM v3: dbuf LDS + counted vmcnt + XCD-bijective swizzle ----------------
template<int OUT_BF16>
__global__ __launch_bounds__(256) void gemm_bt(
    const ushort* __restrict__ A, const ushort* __restrict__ B, void* __restrict__ Cv,
    int K, int lda, int ldb, int ldc,
    long long aB, long long bB, long long cB)
{
  __shared__ ushort As[2][128 * 32];
  __shared__ ushort Bs[2][128 * 32];
  const int tid = threadIdx.x;
  const int lane = tid & 63, wid = tid >> 6;

  const int gx = gridDim.x;
  const int nwg = gx * gridDim.y;
  int l = blockIdx.y * gx + blockIdx.x;
  int tile = l;
  if ((nwg & 7) == 0) tile = (l & 7) * (nwg >> 3) + (l >> 3);
  const int m0 = (tile / gx) * 128, n0 = (tile % gx) * 128;

  A += (size_t)blockIdx.z * aB;
  B += (size_t)blockIdx.z * bB;
  const int wm = (wid >> 1) * 64, wn = (wid & 1) * 64;
  const int fr = lane & 15;
  const int kk = (lane >> 4) * 8;

  auto stage = [&](int k0, int buf) {
#pragma unroll
    for (int i = 0; i < 2; ++i) {
      int c = i * 256 + tid;
      gld_lds16(A + (size_t)(m0 + (c >> 2)) * lda + k0 + (c & 3) * 8, (void*)(&As[buf][0] + c * 8));
    }
#pragma unroll
    for (int i = 0; i < 2; ++i) {
      int c = i * 256 + tid;
      gld_lds16(B + (size_t)(n0 + (c >> 2)) * ldb + k0 + (c & 3) * 8, (void*)(&Bs[buf][0] + c * 8));
    }
  };

  f32x4 acc[4][4] = {};
  const int nt = K >> 5;
  stage(0, 0);
  for (int t = 0; t < nt; ++t) {
    const int cur = t & 1;
    if (t + 1 < nt) {
      stage((t + 1) << 5, cur ^ 1);
      asm volatile("s_waitcnt vmcnt(4)" ::: "memory");
    } else {
      asm volatile("s_waitcnt vmcnt(0)" ::: "memory");
    }
    __builtin_amdgcn_sched_barrier(0);
    __builtin_amdgcn_s_barrier();
    __builtin_amdgcn_sched_barrier(0);

    short8 af[4], bf[4];
#pragma unroll
    for (int x = 0; x < 4; ++x) af[x] = *(const short8*)(&As[cur][0] + (wm + x * 16 + fr) * 32 + kk);
#pragma unroll
    for (int x = 0; x < 4; ++x) bf[x] = *(const short8*)(&Bs[cur][0] + (wn + x * 16 + fr) * 32 + kk);
#pragma unroll
    for (int mi = 0; mi < 4; ++mi)
#pragma unroll
      for (int ni = 0; ni < 4; ++ni)
        acc[mi][ni] = __builtin_amdgcn_mfma_f32_16x16x32_bf16(af[mi], bf[ni], acc[mi][ni], 0, 0, 0);

    __builtin_amdgcn_sched_barrier(0);
    __builtin_amdgcn_s_barrier();
    __builtin_amdgcn_sched_barrier(0);
  }

  const int rb = (lane >> 4) * 4;
#pragma unroll
  for (int mi = 0; mi < 4; ++mi)
#pragma unroll
    for (int ni = 0; ni < 4; ++ni)
#pragma unroll
      for (int r = 0; r < 4; ++r) {
        size_t row = (size_t)(m0 + wm + mi * 16 + rb + r);
        size_t col = (size_t)(n0 + wn + ni * 16 + fr);
        size_t idx = row * (size_t)ldc + col + (size_t)blockIdx.z * cB;
        if (OUT_BF16) ((ushort*)Cv)[idx] = f2bf(acc[mi][ni][r]);
        else          ((float*)Cv)[idx]  = acc[mi][ni][r];
      }
}

// ---------------- RMSNorm (kv_c, bf16 in) + RoPE-k -> k_eff[T][KSTR] bf16 ----------------
__global__ __launch_bounds__(256) void rms_rope_k(
    const ushort* __restrict__ qckv, const float* __restrict__ lnw,
    const float* __restrict__ cosb, const float* __restrict__ sinb,
    ushort* __restrict__ k_eff)
{
  const int t = blockIdx.x, tid = threadIdx.x;
  __shared__ float red[4];
  const size_t base = (size_t)t * QCKV + 3072;
  float v0 = bf2f(qckv[base + tid]);
  float v1 = bf2f(qckv[base + 256 + tid]);
  float ss = v0 * v0 + v1 * v1;
#pragma unroll
  for (int m = 1; m < 64; m <<= 1) ss += __shfl_xor(ss, m);
  if ((tid & 63) == 0) red[tid >> 6] = ss;
  __syncthreads();
  float rn = rsqrtf((red[0] + red[1] + red[2] + red[3]) * (1.0f / 512.0f) + 1e-6f);
  k_eff[(size_t)t * KSTR + tid]       = f2bf(v0 * rn * lnw[tid]);
  k_eff[(size_t)t * KSTR + 256 + tid] = f2bf(v1 * rn * lnw[256 + tid]);
  if (tid < 64) {
    int j = tid;
    int src  = (j < 32) ? 2 * j : 2 * (j - 32) + 1;
    int psrc = (j < 32) ? src + 1 : src - 1;
    float xv = bf2f(qckv[base + 512 + src]);
    float pv = bf2f(qckv[base + 512 + psrc]);
    float c = cosb[t * 64 + j], s = sinb[t * 64 + j];
    k_eff[(size_t)t * KSTR + 512 + j] = f2bf((j < 32) ? xv * c - pv * s : xv * c + pv * s);
  }
}

// ---------------- kvT[b][v][s] = kv_c[b][s][v] (64x64 LDS tiles) ----------------
__global__ __launch_bounds__(256) void transpose_kv(
    const ushort* __restrict__ keff, ushort* __restrict__ kvT)
{
  __shared__ ushort Tl[64][72];
  const int s0 = blockIdx.x * 64, v0 = blockIdx.y * 64, b = blockIdx.z;
  const int tid = threadIdx.x;
#pragma unroll
  for (int i = 0; i < 2; ++i) {
    int c = i * 256 + tid;
    int r = c >> 3, c8 = (c & 7) * 8;
    *(short8*)&Tl[r][c8] = *(const short8*)&keff[((size_t)b * SEQ + s0 + r) * KSTR + v0 + c8];
  }
  __syncthreads();
#pragma unroll
  for (int i = 0; i < 2; ++i) {
    int c = i * 256 + tid;
    int v = c >> 3, s8 = (c & 7) * 8;
    short8 o;
#pragma unroll
    for (int e = 0; e < 8; ++e) o[e] = Tl[s8 + e][v];
    *(short8*)&kvT[((size_t)b * 512 + v0 + v) * SEQ + s0 + s8] = o;
  }
}

// ---------------- RoPE-q -> q_eff[h][t][512..576] ----------------
__global__ void rope_q(const ushort* __restrict__ qb, const float* __restrict__ cosb,
                       const float* __restrict__ sinb, ushort* __restrict__ q_eff)
{
  const int t = blockIdx.x;
  const int h = blockIdx.y * 4 + threadIdx.y;
  const int j = threadIdx.x;
  size_t base = (size_t)t * QCKV + h * 192 + 128;
  int src  = (j < 32) ? 2 * j : 2 * (j - 32) + 1;
  int psrc = (j < 32) ? src + 1 : src - 1;
  float xv = bf2f(qb[base + src]), pv = bf2f(qb[base + psrc]);
  float c = cosb[t * 64 + j], s = sinb[t * 64 + j];
  q_eff[((size_t)h * T_TOK + t) * DQK + 512 + j] = f2bf((j < 32) ? xv * c - pv * s : xv * c + pv * s);
}

// ---------------- Flash attention v9: KB=16, QBLK=64, 2 blocks/CU ----------------
// Same counted-vmcnt 2-barrier skeleton as the proven attn3, but the tile is
// halved (16 keys) so LDS = 76,800 B -> TWO independent blocks per CU: one
// block's MFMA/softmax overlaps the other's barrier/staging stalls.
// Ks rows padded to 640 ushorts so each K stage is a uniform 1280 chunks
// (5/thread, no guards -> wave-uniform vmcnt). PV uses 16x16x16 MFMA (K=16).
__global__ __launch_bounds__(256, 2) void attn7(
    const ushort* __restrict__ q_eff, const ushort* __restrict__ keff,
    const ushort* __restrict__ kvT, ushort* __restrict__ out_lat)
{
  const int pair = blockIdx.x;          // 0..15
  const int h = blockIdx.y, b = blockIdx.z;
  const int tid = threadIdx.x, lane = tid & 63, w = tid >> 6;  // 4 waves
  __shared__ ushort Ks[2][16 * 640];    // 2 x 20,480 B (rows at stride KSTR, tail pad)
  __shared__ ushort Vt[2][512 * 16];    // 2 x 16,384 B, [v][key]
  __shared__ ushort Pl[4][16 * 24];     // 3,072 B, per-wave P (16 rows x 16 keys, stride 24)

  const int fr = lane & 15, g = lane >> 4;

  // stage 16-key K tile: 1280 chunks (1184 real + 96 pad), 5 per thread, uniform
  auto stageK = [&](int kt, int buf) {
    const ushort* ksrc = keff + ((size_t)b * SEQ + (size_t)kt * 16) * KSTR;
    ushort* kd = &Ks[buf][0];
#pragma unroll
    for (int i = 0; i < 5; ++i) {
      int c = i * 256 + tid;
      gld_lds16(ksrc + (size_t)c * 8, (void*)(kd + (size_t)c * 8));
    }
  };
  // stage V^T tile [512][16]: 1024 chunks, 4 per thread, uniform
  auto stageV = [&](int kt, int buf) {
    const ushort* vsrc = kvT + (size_t)b * 512 * SEQ + (size_t)kt * 16;
    ushort* vd = &Vt[buf][0];
#pragma unroll
    for (int i = 0; i < 4; ++i) {
      int c = i * 256 + tid;
      gld_lds16(vsrc + (size_t)(c >> 1) * SEQ + (c & 1) * 8, (void*)(vd + (size_t)c * 8));
    }
  };

  for (int half = 0; half < 2; ++half) {
    const int qb = half ? pair : (31 - pair);
    const int q0 = qb * 64 + w * 16;    // wave's first q row (in batch)

    const ushort* qrow = q_eff + ((size_t)h * T_TOK + (size_t)b * SEQ + q0 + fr) * DQK + g * 8;
    short8 qf[18];
#pragma unroll
    for (int ks = 0; ks < 18; ++ks) qf[ks] = *(const short8*)(qrow + ks * 32);

    f32x4 acc[32] = {};
    float m_s[4] = {-1e30f, -1e30f, -1e30f, -1e30f};
    float l_s[4] = {0.f, 0.f, 0.f, 0.f};

    const int nt = 4 * qb + 4;          // 16-key tiles

    stageK(0, 0);
    stageV(0, 0);

    for (int kt = 0; kt < nt; ++kt) {
      const int cur = kt & 1;
      if (kt + 1 < nt) {
        stageK(kt + 1, cur ^ 1);
        stageV(kt + 1, cur ^ 1);
        // 9 ops of stage(kt+1) stay in flight; stage(kt) drained
        asm volatile("s_waitcnt vmcnt(9)" ::: "memory");
      } else {
        asm volatile("s_waitcnt vmcnt(0)" ::: "memory");
      }
      __builtin_amdgcn_sched_barrier(0);
      __builtin_amdgcn_s_barrier();     // K(kt)+V(kt) visible
      __builtin_amdgcn_sched_barrier(0);

      if (kt * 16 <= q0 + 15) {
        const ushort* Kc = &Ks[cur][0];
        const ushort* Vc = &Vt[cur][0];
        // QK^T: 16 q-rows x 16 keys
        f32x4 s0 = {};
        __builtin_amdgcn_s_setprio(1);
#pragma unroll
        for (int ks = 0; ks < 18; ++ks) {
          short8 b0 = *(const short8*)(Kc + fr * KSTR + ks * 32 + g * 8);
          s0 = __builtin_amdgcn_mfma_f32_16x16x32_bf16(qf[ks], b0, s0, 0, 0, 0);
        }
        __builtin_amdgcn_s_setprio(0);
        const float SC = 0.07216878364870322f;   // 1/sqrt(DN+DR=192)
        const bool diag = (kt * 16 + 15 > q0);
        float sv0[4];
#pragma unroll
        for (int r = 0; r < 4; ++r) {
          int qg = q0 + 4 * g + r;
          float a0 = s0[r] * SC;
          if (diag && (kt * 16 + fr > qg)) a0 = -1e30f;
          sv0[r] = a0;
        }
        float mx[4];
#pragma unroll
        for (int r = 0; r < 4; ++r) {
          float m2 = sv0[r];
          m2 = fmaxf(m2, __shfl_xor(m2, 1));
          m2 = fmaxf(m2, __shfl_xor(m2, 2));
          m2 = fmaxf(m2, __shfl_xor(m2, 4));
          m2 = fmaxf(m2, __shfl_xor(m2, 8));
          mx[r] = m2;
        }
        float need = mx[0] - m_s[0];
#pragma unroll
        for (int r = 1; r < 4; ++r) need = fmaxf(need, mx[r] - m_s[r]);
        if (__any(need > 8.0f)) {
          float rsc[4];
#pragma unroll
          for (int r = 0; r < 4; ++r) {
            float mn = fmaxf(m_s[r], mx[r]);
            rsc[r] = __expf(m_s[r] - mn);
            m_s[r] = mn;
            l_s[r] *= rsc[r];
          }
#pragma unroll
          for (int n2 = 0; n2 < 32; ++n2)
#pragma unroll
            for (int r = 0; r < 4; ++r) acc[n2][r] *= rsc[r];
        }
        float p0[4];
#pragma unroll
        for (int r = 0; r < 4; ++r) {
          p0[r] = __expf(sv0[r] - m_s[r]);
          float ps = p0[r];
          ps += __shfl_xor(ps, 1);
          ps += __shfl_xor(ps, 2);
          ps += __shfl_xor(ps, 4);
          ps += __shfl_xor(ps, 8);
          l_s[r] += ps;
          Pl[w][(4 * g + r) * 24 + fr] = f2bf(p0[r]);
        }
        // PV: A = P[16 rows][16 keys] (lane: row=fr, k=g*4..g*4+3),
        //     B = V[16 keys][16 vdims] (lane: col=fr -> Vt row n2*16+fr, k=g*4..)
        short4v pa = *(const short4v*)(Pl[w] + fr * 24 + g * 4);
        __builtin_amdgcn_s_setprio(1);
#pragma unroll
        for (int n2 = 0; n2 < 32; ++n2) {
          short4v bv = *(const short4v*)(Vc + (n2 * 16 + fr) * 16 + g * 4);
          acc[n2] = MFMA16(pa, bv, acc[n2]);
        }
        __builtin_amdgcn_s_setprio(0);
      }
      __builtin_amdgcn_sched_barrier(0);
      __builtin_amdgcn_s_barrier();     // all reads of buf[cur] done
      __builtin_amdgcn_sched_barrier(0);
    }

    const size_t obase = ((size_t)h * T_TOK + (size_t)b * SEQ + q0) * LAT;
    float inv[4];
#pragma unroll
    for (int r = 0; r < 4; ++r) inv[r] = 1.0f / l_s[r];
#pragma unroll
    for (int n2 = 0; n2 < 32; ++n2)
#pragma unroll
      for (int r = 0; r < 4; ++r)
        out_lat[obase + (size_t)(4 * g + r) * LAT + n2 * 16 + fr] = f2bf(acc[n2][r] * inv[r]);
  }
}

// ---------------- launch ----------------
extern "C" void kernel_launch(void* const* d_in, const int* in_sizes, int n_in,
                              void* d_out, int out_size, void* d_ws, size_t ws_size,
                              hipStream_t stream) {
  const float* hs   = (const float*)d_in[0];
  const float* cosb = (const float*)d_in[1];
  const float* sinb = (const float*)d_in[2];
  const float* qw   = (const float*)d_in[3];
  const float* kvw  = (const float*)d_in[4];
  const float* lnw  = (const float*)d_in[5];
  const float* wuk  = (const float*)d_in[6];
  const float* wuv  = (const float*)d_in[7];
  const float* wo   = (const float*)d_in[8];
  float* out = (float*)d_out;
  char* ws = (char*)d_ws;

  // workspace layout (bytes); out_lat aliases the region dead by attention time
  const size_t o_xb   = 0;              // 16,777,216
  const size_t o_qb   = 16777216;       // 4096x3712 bf16 = 30,408,704
  const size_t o_wq   = 47185920;       // 12,582,912
  const size_t o_wkv  = 59768832;       // 2,621,440 (contiguous after wq)
  const size_t o_ol   = 0;              // out_lat 67,108,864 (alias; above dead by attn)
  const size_t o_wukt = 67108864;       // 2,097,152
  const size_t o_wuvt = 69206016;       // 2,097,152
  const size_t o_wo   = 71303168;       // 8,388,608
  const size_t o_keff = 79691776;       // 4096x592 bf16 = 4,849,664
  const size_t o_qeff = 84541440;       // 16x4096x576 bf16 = 75,497,472
  const size_t o_oh   = 160038912;      // 16,777,216
  const size_t o_kvt  = 176816128;      // 4,194,304 -> ends 181,010,432

  ushort* xb    = (ushort*)(ws + o_xb);
  ushort* qbuf  = (ushort*)(ws + o_qb);
  ushort* wq_b  = (ushort*)(ws + o_wq);
  ushort* wkv_b = (ushort*)(ws + o_wkv);
  ushort* olat  = (ushort*)(ws + o_ol);
  ushort* wukt  = (ushort*)(ws + o_wukt);
  ushort* wuvt  = (ushort*)(ws + o_wuvt);
  ushort* wo_b  = (ushort*)(ws + o_wo);
  ushort* keff  = (ushort*)(ws + o_keff);
  ushort* qeff  = (ushort*)(ws + o_qeff);
  ushort* ohead = (ushort*)(ws + o_oh);
  ushort* kvt   = (ushort*)(ws + o_kvt);

  // 1) casts
  cast4<<<8192, 256, 0, stream>>>(hs, xb, 8388608 / 4);
  cast4<<<6144, 256, 0, stream>>>(qw, wq_b, 6291456 / 4);
  cast_pad_kv<<<1280, 256, 0, stream>>>(kvw, wkv_b);
  cast4<<<4096, 256, 0, stream>>>(wo, wo_b, 4194304 / 4);
  cast_wuk<<<4096, 256, 0, stream>>>(wuk, wukt);
  cast_wuv<<<4096, 256, 0, stream>>>(wuv, wuvt);

  // 2) [q | ckv] = x @ [q_proj_w ; kv_a_proj_w_padded]^T  (bf16 out, merged)
  gemm_bt<1><<<dim3(29, 32, 1), 256, 0, stream>>>(xb, wq_b, qbuf, 2048, 2048, 2048, QCKV, 0, 0, 0);
  // 3) RMSNorm + RoPE-k -> k_eff (reads ckv cols of qbuf)
  rms_rope_k<<<4096, 256, 0, stream>>>(qbuf, lnw, cosb, sinb, keff);
  // 3b) kvT = kv_c^T per batch
  transpose_kv<<<dim3(32, 8, 2), 256, 0, stream>>>(keff, kvt);
  // 4) RoPE-q -> q_eff[., 512..576]
  rope_q<<<dim3(4096, 4, 1), dim3(64, 4, 1), 0, stream>>>(qbuf, cosb, sinb, qeff);
  // 5) q_lat per head -> q_eff[., 0..512]
  gemm_bt<1><<<dim3(4, 32, 16), 256, 0, stream>>>(qbuf, wukt, qeff, 128, QCKV, 128, 576,
                                                  192LL, 65536LL, 2359296LL);
  // 6) attention -> out_lat
  attn7<<<dim3(16, 16, 2), 256, 0, stream>>>(qeff, keff, kvt, olat);
  // 7) o_head = out_lat @ W_UV (per head)
  gemm_bt<1><<<dim3(1, 32, 16), 256, 0, stream>>>(olat, wuvt, ohead, 512, 512, 512, 2048,
                                                  2097152LL, 65536LL, 128LL);
  // 8) out = o_head @ o_proj_w^T (f32 out)
  gemm_bt<0><<<dim3(16, 32, 1), 256, 0, stream>>>(ohead, wo_b, out, 2048, 2048, 2048, 2048, 0, 0, 0);
}

// Round 14
// 625.231 us; speedup vs baseline: 1.1724x; 1.1724x over previous
//
#include <hip/hip_runtime.h>
#include <stdint.h>

// Problem constants
#define T_TOK 4096   // B*S
#define HIDD  2048
#define NH    16
#define DNN   128
#define DRR   64
#define DVV   128
#define LAT   512
#define DQK   576    // LAT + DR
#define SEQ   2048
#define NB    2
#define KSTR  592    // padded keff row stride (ushorts) = 74 chunks of 16B
#define KCH   2368   // 16B chunks per K tile (32*KSTR/8)
#define QCKV  3712   // merged q(3072) + ckv(640) row stride

typedef __attribute__((__ext_vector_type__(8))) short short8;
typedef __attribute__((__ext_vector_type__(4))) float f32x4;

__device__ __forceinline__ float bf2f(ushort u) {
  union { uint32_t i; float f; } v; v.i = ((uint32_t)u) << 16; return v.f;
}
__device__ __forceinline__ ushort f2bf(float f) {
  union { float f; uint32_t i; } v; v.f = f;
  uint32_t r = v.i + 0x7FFF + ((v.i >> 16) & 1);
  return (ushort)(r >> 16);
}

__device__ __forceinline__ void gld_lds16(const void* g, void* l) {
  __builtin_amdgcn_global_load_lds((const __attribute__((address_space(1))) void*)g,
                                   (__attribute__((address_space(3))) void*)l, 16, 0, 0);
}

// ---------------- cast kernels ----------------
__global__ void cast4(const float* __restrict__ in, ushort* __restrict__ out, int n4) {
  int i = blockIdx.x * blockDim.x + threadIdx.x;
  if (i >= n4) return;
  float4 v = ((const float4*)in)[i];
  ushort4 o; o.x = f2bf(v.x); o.y = f2bf(v.y); o.z = f2bf(v.z); o.w = f2bf(v.w);
  ((ushort4*)out)[i] = o;
}

// kv_a_proj_w (576x2048) -> padded (640x2048) bf16, pad rows zero
__global__ void cast_pad_kv(const float* __restrict__ in, ushort* __restrict__ out) {
  int i = blockIdx.x * 256 + threadIdx.x;     // over 640*2048/4
  int row = (i * 4) >> 11;
  ushort4 o;
  if (row < 576) {
    float4 v = ((const float4*)in)[i];
    o.x = f2bf(v.x); o.y = f2bf(v.y); o.z = f2bf(v.z); o.w = f2bf(v.w);
  } else { o.x = 0; o.y = 0; o.z = 0; o.w = 0; }
  ((ushort4*)out)[i] = o;
}

// wuk_t[h][l][d] = W_UK_T[h][d][l]
__global__ void cast_wuk(const float* __restrict__ in, ushort* __restrict__ out) {
  int o = blockIdx.x * 256 + threadIdx.x;   // 16*512*128
  int d = o & 127, l = (o >> 7) & 511, h = o >> 16;
  out[o] = f2bf(in[((size_t)(h * 128 + d)) * 512 + l]);
}
// wuv_t[h][v][l] = W_UV[h][l][v]
__global__ void cast_wuv(const float* __restrict__ in, ushort* __restrict__ out) {
  int o = blockIdx.x * 256 + threadIdx.x;   // 16*128*512
  int l = o & 511, v = (o >> 9) & 127, h = o >> 16;
  out[o] = f2bf(in[((size_t)(h * 512 + l)) * 128 + v]);
}

// ---------------- GEMM v3: dbuf LDS + counted vmcnt + XCD-bijective swizzle ----------------
template<int OUT_BF16>
__global__ __launch_bounds__(256) void gemm_bt(
    const ushort* __restrict__ A, const ushort* __restrict__ B, void* __restrict__ Cv,
    int K, int lda, int ldb, int ldc,
    long long aB, long long bB, long long cB)
{
  __shared__ ushort As[2][128 * 32];
  __shared__ ushort Bs[2][128 * 32];
  const int tid = threadIdx.x;
  const int lane = tid & 63, wid = tid >> 6;

  const int gx = gridDim.x;
  const int nwg = gx * gridDim.y;
  int l = blockIdx.y * gx + blockIdx.x;
  int tile = l;
  if ((nwg & 7) == 0) tile = (l & 7) * (nwg >> 3) + (l >> 3);
  const int m0 = (tile / gx) * 128, n0 = (tile % gx) * 128;

  A += (size_t)blockIdx.z * aB;
  B += (size_t)blockIdx.z * bB;
  const int wm = (wid >> 1) * 64, wn = (wid & 1) * 64;
  const int fr = lane & 15;
  const int kk = (lane >> 4) * 8;

  auto stage = [&](int k0, int buf) {
#pragma unroll
    for (int i = 0; i < 2; ++i) {
      int c = i * 256 + tid;
      gld_lds16(A + (size_t)(m0 + (c >> 2)) * lda + k0 + (c & 3) * 8, (void*)(&As[buf][0] + c * 8));
    }
#pragma unroll
    for (int i = 0; i < 2; ++i) {
      int c = i * 256 + tid;
      gld_lds16(B + (size_t)(n0 + (c >> 2)) * ldb + k0 + (c & 3) * 8, (void*)(&Bs[buf][0] + c * 8));
    }
  };

  f32x4 acc[4][4] = {};
  const int nt = K >> 5;
  stage(0, 0);
  for (int t = 0; t < nt; ++t) {
    const int cur = t & 1;
    if (t + 1 < nt) {
      stage((t + 1) << 5, cur ^ 1);
      asm volatile("s_waitcnt vmcnt(4)" ::: "memory");
    } else {
      asm volatile("s_waitcnt vmcnt(0)" ::: "memory");
    }
    __builtin_amdgcn_sched_barrier(0);
    __builtin_amdgcn_s_barrier();
    __builtin_amdgcn_sched_barrier(0);

    short8 af[4], bf[4];
#pragma unroll
    for (int x = 0; x < 4; ++x) af[x] = *(const short8*)(&As[cur][0] + (wm + x * 16 + fr) * 32 + kk);
#pragma unroll
    for (int x = 0; x < 4; ++x) bf[x] = *(const short8*)(&Bs[cur][0] + (wn + x * 16 + fr) * 32 + kk);
#pragma unroll
    for (int mi = 0; mi < 4; ++mi)
#pragma unroll
      for (int ni = 0; ni < 4; ++ni)
        acc[mi][ni] = __builtin_amdgcn_mfma_f32_16x16x32_bf16(af[mi], bf[ni], acc[mi][ni], 0, 0, 0);

    __builtin_amdgcn_sched_barrier(0);
    __builtin_amdgcn_s_barrier();
    __builtin_amdgcn_sched_barrier(0);
  }

  const int rb = (lane >> 4) * 4;
#pragma unroll
  for (int mi = 0; mi < 4; ++mi)
#pragma unroll
    for (int ni = 0; ni < 4; ++ni)
#pragma unroll
      for (int r = 0; r < 4; ++r) {
        size_t row = (size_t)(m0 + wm + mi * 16 + rb + r);
        size_t col = (size_t)(n0 + wn + ni * 16 + fr);
        size_t idx = row * (size_t)ldc + col + (size_t)blockIdx.z * cB;
        if (OUT_BF16) ((ushort*)Cv)[idx] = f2bf(acc[mi][ni][r]);
        else          ((float*)Cv)[idx]  = acc[mi][ni][r];
      }
}

// ---------------- RMSNorm (kv_c, bf16 in) + RoPE-k -> k_eff[T][KSTR] bf16 ----------------
__global__ __launch_bounds__(256) void rms_rope_k(
    const ushort* __restrict__ qckv, const float* __restrict__ lnw,
    const float* __restrict__ cosb, const float* __restrict__ sinb,
    ushort* __restrict__ k_eff)
{
  const int t = blockIdx.x, tid = threadIdx.x;
  __shared__ float red[4];
  const size_t base = (size_t)t * QCKV + 3072;
  float v0 = bf2f(qckv[base + tid]);
  float v1 = bf2f(qckv[base + 256 + tid]);
  float ss = v0 * v0 + v1 * v1;
#pragma unroll
  for (int m = 1; m < 64; m <<= 1) ss += __shfl_xor(ss, m);
  if ((tid & 63) == 0) red[tid >> 6] = ss;
  __syncthreads();
  float rn = rsqrtf((red[0] + red[1] + red[2] + red[3]) * (1.0f / 512.0f) + 1e-6f);
  k_eff[(size_t)t * KSTR + tid]       = f2bf(v0 * rn * lnw[tid]);
  k_eff[(size_t)t * KSTR + 256 + tid] = f2bf(v1 * rn * lnw[256 + tid]);
  if (tid < 64) {
    int j = tid;
    int src  = (j < 32) ? 2 * j : 2 * (j - 32) + 1;
    int psrc = (j < 32) ? src + 1 : src - 1;
    float xv = bf2f(qckv[base + 512 + src]);
    float pv = bf2f(qckv[base + 512 + psrc]);
    float c = cosb[t * 64 + j], s = sinb[t * 64 + j];
    k_eff[(size_t)t * KSTR + 512 + j] = f2bf((j < 32) ? xv * c - pv * s : xv * c + pv * s);
  }
}

// ---------------- kvT[b][v][s] = kv_c[b][s][v] (64x64 LDS tiles) ----------------
__global__ __launch_bounds__(256) void transpose_kv(
    const ushort* __restrict__ keff, ushort* __restrict__ kvT)
{
  __shared__ ushort Tl[64][72];
  const int s0 = blockIdx.x * 64, v0 = blockIdx.y * 64, b = blockIdx.z;
  const int tid = threadIdx.x;
#pragma unroll
  for (int i = 0; i < 2; ++i) {
    int c = i * 256 + tid;
    int r = c >> 3, c8 = (c & 7) * 8;
    *(short8*)&Tl[r][c8] = *(const short8*)&keff[((size_t)b * SEQ + s0 + r) * KSTR + v0 + c8];
  }
  __syncthreads();
#pragma unroll
  for (int i = 0; i < 2; ++i) {
    int c = i * 256 + tid;
    int v = c >> 3, s8 = (c & 7) * 8;
    short8 o;
#pragma unroll
    for (int e = 0; e < 8; ++e) o[e] = Tl[s8 + e][v];
    *(short8*)&kvT[((size_t)b * 512 + v0 + v) * SEQ + s0 + s8] = o;
  }
}

// ---------------- RoPE-q -> q_eff[h][t][512..576] ----------------
__global__ void rope_q(const ushort* __restrict__ qb, const float* __restrict__ cosb,
                       const float* __restrict__ sinb, ushort* __restrict__ q_eff)
{
  const int t = blockIdx.x;
  const int h = blockIdx.y * 4 + threadIdx.y;
  const int j = threadIdx.x;
  size_t base = (size_t)t * QCKV + h * 192 + 128;
  int src  = (j < 32) ? 2 * j : 2 * (j - 32) + 1;
  int psrc = (j < 32) ? src + 1 : src - 1;
  float xv = bf2f(qb[base + src]), pv = bf2f(qb[base + psrc]);
  float c = cosb[t * 64 + j], s = sinb[t * 64 + j];
  q_eff[((size_t)h * T_TOK + t) * DQK + 512 + j] = f2bf((j < 32) ? xv * c - pv * s : xv * c + pv * s);
}

// ---------------- Flash attention v5 + T5 setprio (round-10/12 proven) ----------------
__global__ __launch_bounds__(512, 2) void attn3(
    const ushort* __restrict__ q_eff, const ushort* __restrict__ keff,
    const ushort* __restrict__ kvT, ushort* __restrict__ out_lat)
{
  const int pair = blockIdx.x;          // 0..7
  const int h = blockIdx.y, b = blockIdx.z;
  const int tid = threadIdx.x, lane = tid & 63, w = tid >> 6;
  __shared__ ushort Ks[2][32 * KSTR];   // 2 x 37888 B
  __shared__ ushort Vt[2][512 * 32];    // 2 x 32768 B, [v][key] stride 32
  __shared__ ushort Pl[8][16 * 40];     // 10240 B, per-wave P

  const int fr = lane & 15, g = lane >> 4;

  auto stageK = [&](int kt, int buf) {
    const ushort* ksrc = keff + ((size_t)b * SEQ + (size_t)kt * 32) * KSTR;
    ushort* kd = &Ks[buf][0];
#pragma unroll
    for (int i = 0; i < 5; ++i) {
      int c0 = w * 320 + i * 64;
      if (c0 < KCH) {
        int c = c0 + lane;
        gld_lds16(ksrc + (size_t)c * 8, (void*)(kd + (size_t)c * 8));
      }
    }
  };
  auto stageV = [&](int kt, int buf) {
    const ushort* vsrc = kvT + (size_t)b * 512 * SEQ + (size_t)kt * 32;
    ushort* vd = &Vt[buf][0];
#pragma unroll
    for (int i = 0; i < 4; ++i) {
      int c = w * 256 + i * 64 + lane;
      gld_lds16(vsrc + (size_t)(c >> 2) * SEQ + (c & 3) * 8, (void*)(vd + (size_t)c * 8));
    }
  };

  for (int half = 0; half < 2; ++half) {
    const int qb = half ? pair : (15 - pair);
    const int q0 = qb * 128 + w * 16;   // wave's first q row (in batch)

    const ushort* qrow = q_eff + ((size_t)h * T_TOK + (size_t)b * SEQ + q0 + fr) * DQK + g * 8;
    short8 qf[18];
#pragma unroll
    for (int ks = 0; ks < 18; ++ks) qf[ks] = *(const short8*)(qrow + ks * 32);

    f32x4 acc[32] = {};
    float m_s[4] = {-1e30f, -1e30f, -1e30f, -1e30f};
    float l_s[4] = {0.f, 0.f, 0.f, 0.f};

    const int nt = 4 * qb + 4;

    stageK(0, 0);
    stageV(0, 0);

    for (int kt = 0; kt < nt; ++kt) {
      const int cur = kt & 1;
      if (kt + 1 < nt) {
        stageK(kt + 1, cur ^ 1);
        stageV(kt + 1, cur ^ 1);
        if (w == 7) asm volatile("s_waitcnt vmcnt(6)" ::: "memory");
        else        asm volatile("s_waitcnt vmcnt(9)" ::: "memory");
      } else {
        asm volatile("s_waitcnt vmcnt(0)" ::: "memory");
      }
      __builtin_amdgcn_sched_barrier(0);
      __builtin_amdgcn_s_barrier();
      __builtin_amdgcn_sched_barrier(0);

      if (kt * 32 <= q0 + 15) {
        const ushort* Kc = &Ks[cur][0];
        const ushort* Vc = &Vt[cur][0];
        f32x4 s0 = {}, s1 = {};
        __builtin_amdgcn_s_setprio(1);
#pragma unroll
        for (int ks = 0; ks < 18; ++ks) {
          short8 b0 = *(const short8*)(Kc + (0 * 16 + fr) * KSTR + ks * 32 + g * 8);
          short8 b1 = *(const short8*)(Kc + (1 * 16 + fr) * KSTR + ks * 32 + g * 8);
          s0 = __builtin_amdgcn_mfma_f32_16x16x32_bf16(qf[ks], b0, s0, 0, 0, 0);
          s1 = __builtin_amdgcn_mfma_f32_16x16x32_bf16(qf[ks], b1, s1, 0, 0, 0);
        }
        __builtin_amdgcn_s_setprio(0);
        const float SC = 0.07216878364870322f;   // 1/sqrt(DN+DR=192)
        const bool diag = (kt * 32 + 31 > q0);
        float sv0[4], sv1[4];
#pragma unroll
        for (int r = 0; r < 4; ++r) {
          int qg = q0 + 4 * g + r;
          float a0 = s0[r] * SC, a1 = s1[r] * SC;
          if (diag) {
            if (kt * 32 + fr > qg)      a0 = -1e30f;
            if (kt * 32 + 16 + fr > qg) a1 = -1e30f;
          }
          sv0[r] = a0; sv1[r] = a1;
        }
        float mx[4];
#pragma unroll
        for (int r = 0; r < 4; ++r) {
          float m2 = fmaxf(sv0[r], sv1[r]);
          m2 = fmaxf(m2, __shfl_xor(m2, 1));
          m2 = fmaxf(m2, __shfl_xor(m2, 2));
          m2 = fmaxf(m2, __shfl_xor(m2, 4));
          m2 = fmaxf(m2, __shfl_xor(m2, 8));
          mx[r] = m2;
        }
        float need = mx[0] - m_s[0];
#pragma unroll
        for (int r = 1; r < 4; ++r) need = fmaxf(need, mx[r] - m_s[r]);
        if (__any(need > 8.0f)) {
          float rsc[4];
#pragma unroll
          for (int r = 0; r < 4; ++r) {
            float mn = fmaxf(m_s[r], mx[r]);
            rsc[r] = __expf(m_s[r] - mn);
            m_s[r] = mn;
            l_s[r] *= rsc[r];
          }
#pragma unroll
          for (int n2 = 0; n2 < 32; ++n2)
#pragma unroll
            for (int r = 0; r < 4; ++r) acc[n2][r] *= rsc[r];
        }
        float p0[4], p1[4];
#pragma unroll
        for (int r = 0; r < 4; ++r) {
          p0[r] = __expf(sv0[r] - m_s[r]);
          p1[r] = __expf(sv1[r] - m_s[r]);
          float ps = p0[r] + p1[r];
          ps += __shfl_xor(ps, 1);
          ps += __shfl_xor(ps, 2);
          ps += __shfl_xor(ps, 4);
          ps += __shfl_xor(ps, 8);
          l_s[r] += ps;
          Pl[w][(4 * g + r) * 40 + fr]      = f2bf(p0[r]);
          Pl[w][(4 * g + r) * 40 + 16 + fr] = f2bf(p1[r]);
        }
        short8 pa = *(const short8*)(Pl[w] + fr * 40 + g * 8);
        __builtin_amdgcn_s_setprio(1);
#pragma unroll
        for (int n2 = 0; n2 < 32; ++n2) {
          short8 bv = *(const short8*)(Vc + (n2 * 16 + fr) * 32 + g * 8);
          acc[n2] = __builtin_amdgcn_mfma_f32_16x16x32_bf16(pa, bv, acc[n2], 0, 0, 0);
        }
        __builtin_amdgcn_s_setprio(0);
      }
      __builtin_amdgcn_sched_barrier(0);
      __builtin_amdgcn_s_barrier();
      __builtin_amdgcn_sched_barrier(0);
    }

    const size_t obase = ((size_t)h * T_TOK + (size_t)b * SEQ + q0) * LAT;
    float inv[4];
#pragma unroll
    for (int r = 0; r < 4; ++r) inv[r] = 1.0f / l_s[r];
#pragma unroll
    for (int n2 = 0; n2 < 32; ++n2)
#pragma unroll
      for (int r = 0; r < 4; ++r)
        out_lat[obase + (size_t)(4 * g + r) * LAT + n2 * 16 + fr] = f2bf(acc[n2][r] * inv[r]);
  }
}

// ---------------- launch ----------------
extern "C" void kernel_launch(void* const* d_in, const int* in_sizes, int n_in,
                              void* d_out, int out_size, void* d_ws, size_t ws_size,
                              hipStream_t stream) {
  const float* hs   = (const float*)d_in[0];
  const float* cosb = (const float*)d_in[1];
  const float* sinb = (const float*)d_in[2];
  const float* qw   = (const float*)d_in[3];
  const float* kvw  = (const float*)d_in[4];
  const float* lnw  = (const float*)d_in[5];
  const float* wuk  = (const float*)d_in[6];
  const float* wuv  = (const float*)d_in[7];
  const float* wo   = (const float*)d_in[8];
  float* out = (float*)d_out;
  char* ws = (char*)d_ws;

  // workspace layout (bytes); out_lat aliases the region dead by attention time
  const size_t o_xb   = 0;              // 16,777,216
  const size_t o_qb   = 16777216;       // 4096x3712 bf16 = 30,408,704
  const size_t o_wq   = 47185920;       // 12,582,912
  const size_t o_wkv  = 59768832;       // 2,621,440 (contiguous after wq)
  const size_t o_ol   = 0;              // out_lat 67,108,864 (alias; above dead by attn)
  const size_t o_wukt = 67108864;       // 2,097,152
  const size_t o_wuvt = 69206016;       // 2,097,152
  const size_t o_wo   = 71303168;       // 8,388,608
  const size_t o_keff = 79691776;       // 4096x592 bf16 = 4,849,664
  const size_t o_qeff = 84541440;       // 16x4096x576 bf16 = 75,497,472
  const size_t o_oh   = 160038912;      // 16,777,216
  const size_t o_kvt  = 176816128;      // 4,194,304 -> ends 181,010,432

  ushort* xb    = (ushort*)(ws + o_xb);
  ushort* qbuf  = (ushort*)(ws + o_qb);
  ushort* wq_b  = (ushort*)(ws + o_wq);
  ushort* wkv_b = (ushort*)(ws + o_wkv);
  ushort* olat  = (ushort*)(ws + o_ol);
  ushort* wukt  = (ushort*)(ws + o_wukt);
  ushort* wuvt  = (ushort*)(ws + o_wuvt);
  ushort* wo_b  = (ushort*)(ws + o_wo);
  ushort* keff  = (ushort*)(ws + o_keff);
  ushort* qeff  = (ushort*)(ws + o_qeff);
  ushort* ohead = (ushort*)(ws + o_oh);
  ushort* kvt   = (ushort*)(ws + o_kvt);

  // 1) casts
  cast4<<<8192, 256, 0, stream>>>(hs, xb, 8388608 / 4);
  cast4<<<6144, 256, 0, stream>>>(qw, wq_b, 6291456 / 4);
  cast_pad_kv<<<1280, 256, 0, stream>>>(kvw, wkv_b);
  cast4<<<4096, 256, 0, stream>>>(wo, wo_b, 4194304 / 4);
  cast_wuk<<<4096, 256, 0, stream>>>(wuk, wukt);
  cast_wuv<<<4096, 256, 0, stream>>>(wuv, wuvt);

  // 2) [q | ckv] = x @ [q_proj_w ; kv_a_proj_w_padded]^T  (bf16 out, merged)
  gemm_bt<1><<<dim3(29, 32, 1), 256, 0, stream>>>(xb, wq_b, qbuf, 2048, 2048, 2048, QCKV, 0, 0, 0);
  // 3) RMSNorm + RoPE-k -> k_eff (reads ckv cols of qbuf)
  rms_rope_k<<<4096, 256, 0, stream>>>(qbuf, lnw, cosb, sinb, keff);
  // 3b) kvT = kv_c^T per batch
  transpose_kv<<<dim3(32, 8, 2), 256, 0, stream>>>(keff, kvt);
  // 4) RoPE-q -> q_eff[., 512..576]
  rope_q<<<dim3(4096, 4, 1), dim3(64, 4, 1), 0, stream>>>(qbuf, cosb, sinb, qeff);
  // 5) q_lat per head -> q_eff[., 0..512]
  gemm_bt<1><<<dim3(4, 32, 16), 256, 0, stream>>>(qbuf, wukt, qeff, 128, QCKV, 128, 576,
                                                  192LL, 65536LL, 2359296LL);
  // 6) attention -> out_lat
  attn3<<<dim3(8, 16, 2), 512, 0, stream>>>(qeff, keff, kvt, olat);
  // 7) o_head = out_lat @ W_UV (per head)
  gemm_bt<1><<<dim3(1, 32, 16), 256, 0, stream>>>(olat, wuvt, ohead, 512, 512, 512, 2048,
                                                  2097152LL, 65536LL, 128LL);
  // 8) out = o_head @ o_proj_w^T (f32 out)
  gemm_bt<0><<<dim3(16, 32, 1), 256, 0, stream>>>(ohead, wo_b, out, 2048, 2048, 2048, 2048, 0, 0, 0);
}

// Round 15
// 618.683 us; speedup vs baseline: 1.1848x; 1.0106x over previous
//
#include <hip/hip_runtime.h>
#include <stdint.h>

// Problem constants
#define T_TOK 4096   // B*S
#define HIDD  2048
#define NH    16
#define DNN   128
#define DRR   64
#define DVV   128
#define LAT   512
#define DQK   576    // LAT + DR
#define SEQ   2048
#define NB    2
#define KSTR  592    // padded keff row stride (ushorts) = 74 chunks of 16B
#define KCH   2368   // 16B chunks per K tile (32*KSTR/8)
#define QCKV  3712   // merged q(3072) + ckv(640) row stride

typedef __attribute__((__ext_vector_type__(8))) short short8;
typedef __attribute__((__ext_vector_type__(4))) float f32x4;

__device__ __forceinline__ float bf2f(ushort u) {
  union { uint32_t i; float f; } v; v.i = ((uint32_t)u) << 16; return v.f;
}
__device__ __forceinline__ ushort f2bf(float f) {
  union { float f; uint32_t i; } v; v.f = f;
  uint32_t r = v.i + 0x7FFF + ((v.i >> 16) & 1);
  return (ushort)(r >> 16);
}

__device__ __forceinline__ void gld_lds16(const void* g, void* l) {
  __builtin_amdgcn_global_load_lds((const __attribute__((address_space(1))) void*)g,
                                   (__attribute__((address_space(3))) void*)l, 16, 0, 0);
}

// ---------------- cast kernels ----------------
__global__ void cast4(const float* __restrict__ in, ushort* __restrict__ out, int n4) {
  int i = blockIdx.x * blockDim.x + threadIdx.x;
  if (i >= n4) return;
  float4 v = ((const float4*)in)[i];
  ushort4 o; o.x = f2bf(v.x); o.y = f2bf(v.y); o.z = f2bf(v.z); o.w = f2bf(v.w);
  ((ushort4*)out)[i] = o;
}

// kv_a_proj_w (576x2048) -> padded (640x2048) bf16, pad rows zero
__global__ void cast_pad_kv(const float* __restrict__ in, ushort* __restrict__ out) {
  int i = blockIdx.x * 256 + threadIdx.x;     // over 640*2048/4
  int row = (i * 4) >> 11;
  ushort4 o;
  if (row < 576) {
    float4 v = ((const float4*)in)[i];
    o.x = f2bf(v.x); o.y = f2bf(v.y); o.z = f2bf(v.z); o.w = f2bf(v.w);
  } else { o.x = 0; o.y = 0; o.z = 0; o.w = 0; }
  ((ushort4*)out)[i] = o;
}

// merged: blocks 0..4095 -> wuk_t[h][l][d] = W_UK_T[h][d][l]
//         blocks 4096..8191 -> wuv_t[h][v][l] = W_UV[h][l][v]
__global__ void cast_wukv(const float* __restrict__ wuk, const float* __restrict__ wuv,
                          ushort* __restrict__ outk, ushort* __restrict__ outv) {
  if (blockIdx.x < 4096) {
    int o = blockIdx.x * 256 + threadIdx.x;   // 16*512*128
    int d = o & 127, l = (o >> 7) & 511, h = o >> 16;
    outk[o] = f2bf(wuk[((size_t)(h * 128 + d)) * 512 + l]);
  } else {
    int o = (blockIdx.x - 4096) * 256 + threadIdx.x;   // 16*128*512
    int l = o & 511, v = (o >> 9) & 127, h = o >> 16;
    outv[o] = f2bf(wuv[((size_t)(h * 512 + l)) * 128 + v]);
  }
}

// ---------------- GEMM v3: dbuf LDS + counted vmcnt + XCD-bijective swizzle ----------------
template<int OUT_BF16>
__global__ __launch_bounds__(256) void gemm_bt(
    const ushort* __restrict__ A, const ushort* __restrict__ B, void* __restrict__ Cv,
    int K, int lda, int ldb, int ldc,
    long long aB, long long bB, long long cB)
{
  __shared__ ushort As[2][128 * 32];
  __shared__ ushort Bs[2][128 * 32];
  const int tid = threadIdx.x;
  const int lane = tid & 63, wid = tid >> 6;

  const int gx = gridDim.x;
  const int nwg = gx * gridDim.y;
  int l = blockIdx.y * gx + blockIdx.x;
  int tile = l;
  if ((nwg & 7) == 0) tile = (l & 7) * (nwg >> 3) + (l >> 3);
  const int m0 = (tile / gx) * 128, n0 = (tile % gx) * 128;

  A += (size_t)blockIdx.z * aB;
  B += (size_t)blockIdx.z * bB;
  const int wm = (wid >> 1) * 64, wn = (wid & 1) * 64;
  const int fr = lane & 15;
  const int kk = (lane >> 4) * 8;

  auto stage = [&](int k0, int buf) {
#pragma unroll
    for (int i = 0; i < 2; ++i) {
      int c = i * 256 + tid;
      gld_lds16(A + (size_t)(m0 + (c >> 2)) * lda + k0 + (c & 3) * 8, (void*)(&As[buf][0] + c * 8));
    }
#pragma unroll
    for (int i = 0; i < 2; ++i) {
      int c = i * 256 + tid;
      gld_lds16(B + (size_t)(n0 + (c >> 2)) * ldb + k0 + (c & 3) * 8, (void*)(&Bs[buf][0] + c * 8));
    }
  };

  f32x4 acc[4][4] = {};
  const int nt = K >> 5;
  stage(0, 0);
  for (int t = 0; t < nt; ++t) {
    const int cur = t & 1;
    if (t + 1 < nt) {
      stage((t + 1) << 5, cur ^ 1);
      asm volatile("s_waitcnt vmcnt(4)" ::: "memory");
    } else {
      asm volatile("s_waitcnt vmcnt(0)" ::: "memory");
    }
    __builtin_amdgcn_sched_barrier(0);
    __builtin_amdgcn_s_barrier();
    __builtin_amdgcn_sched_barrier(0);

    short8 af[4], bf[4];
#pragma unroll
    for (int x = 0; x < 4; ++x) af[x] = *(const short8*)(&As[cur][0] + (wm + x * 16 + fr) * 32 + kk);
#pragma unroll
    for (int x = 0; x < 4; ++x) bf[x] = *(const short8*)(&Bs[cur][0] + (wn + x * 16 + fr) * 32 + kk);
#pragma unroll
    for (int mi = 0; mi < 4; ++mi)
#pragma unroll
      for (int ni = 0; ni < 4; ++ni)
        acc[mi][ni] = __builtin_amdgcn_mfma_f32_16x16x32_bf16(af[mi], bf[ni], acc[mi][ni], 0, 0, 0);

    __builtin_amdgcn_sched_barrier(0);
    __builtin_amdgcn_s_barrier();
    __builtin_amdgcn_sched_barrier(0);
  }

  const int rb = (lane >> 4) * 4;
#pragma unroll
  for (int mi = 0; mi < 4; ++mi)
#pragma unroll
    for (int ni = 0; ni < 4; ++ni)
#pragma unroll
      for (int r = 0; r < 4; ++r) {
        size_t row = (size_t)(m0 + wm + mi * 16 + rb + r);
        size_t col = (size_t)(n0 + wn + ni * 16 + fr);
        size_t idx = row * (size_t)ldc + col + (size_t)blockIdx.z * cB;
        if (OUT_BF16) ((ushort*)Cv)[idx] = f2bf(acc[mi][ni][r]);
        else          ((float*)Cv)[idx]  = acc[mi][ni][r];
      }
}

// ---------------- RMSNorm + RoPE-k + RoPE-q (fused, one block per token) ----------------
__global__ __launch_bounds__(256) void rms_rope_kq(
    const ushort* __restrict__ qckv, const float* __restrict__ lnw,
    const float* __restrict__ cosb, const float* __restrict__ sinb,
    ushort* __restrict__ k_eff, ushort* __restrict__ q_eff)
{
  const int t = blockIdx.x, tid = threadIdx.x;
  __shared__ float red[4];
  const size_t base = (size_t)t * QCKV + 3072;
  float v0 = bf2f(qckv[base + tid]);
  float v1 = bf2f(qckv[base + 256 + tid]);
  float ss = v0 * v0 + v1 * v1;
#pragma unroll
  for (int m = 1; m < 64; m <<= 1) ss += __shfl_xor(ss, m);
  if ((tid & 63) == 0) red[tid >> 6] = ss;

  // ---- RoPE-q (independent of the reduction): 16 heads x 64 dims = 4 items/thread ----
#pragma unroll
  for (int i = 0; i < 4; ++i) {
    int item = i * 256 + tid;           // 0..1023
    int hh = item >> 6, j = item & 63;
    size_t qb = (size_t)t * QCKV + hh * 192 + 128;
    int src  = (j < 32) ? 2 * j : 2 * (j - 32) + 1;
    int psrc = (j < 32) ? src + 1 : src - 1;
    float xv = bf2f(qckv[qb + src]), pv = bf2f(qckv[qb + psrc]);
    float c = cosb[t * 64 + j], s = sinb[t * 64 + j];
    q_eff[((size_t)hh * T_TOK + t) * DQK + 512 + j] = f2bf((j < 32) ? xv * c - pv * s : xv * c + pv * s);
  }

  __syncthreads();
  float rn = rsqrtf((red[0] + red[1] + red[2] + red[3]) * (1.0f / 512.0f) + 1e-6f);
  k_eff[(size_t)t * KSTR + tid]       = f2bf(v0 * rn * lnw[tid]);
  k_eff[(size_t)t * KSTR + 256 + tid] = f2bf(v1 * rn * lnw[256 + tid]);
  if (tid < 64) {
    int j = tid;
    int src  = (j < 32) ? 2 * j : 2 * (j - 32) + 1;
    int psrc = (j < 32) ? src + 1 : src - 1;
    float xv = bf2f(qckv[base + 512 + src]);
    float pv = bf2f(qckv[base + 512 + psrc]);
    float c = cosb[t * 64 + j], s = sinb[t * 64 + j];
    k_eff[(size_t)t * KSTR + 512 + j] = f2bf((j < 32) ? xv * c - pv * s : xv * c + pv * s);
  }
}

// ---------------- kvT[b][v][s] = kv_c[b][s][v] (64x64 LDS tiles) ----------------
__global__ __launch_bounds__(256) void transpose_kv(
    const ushort* __restrict__ keff, ushort* __restrict__ kvT)
{
  __shared__ ushort Tl[64][72];
  const int s0 = blockIdx.x * 64, v0 = blockIdx.y * 64, b = blockIdx.z;
  const int tid = threadIdx.x;
#pragma unroll
  for (int i = 0; i < 2; ++i) {
    int c = i * 256 + tid;
    int r = c >> 3, c8 = (c & 7) * 8;
    *(short8*)&Tl[r][c8] = *(const short8*)&keff[((size_t)b * SEQ + s0 + r) * KSTR + v0 + c8];
  }
  __syncthreads();
#pragma unroll
  for (int i = 0; i < 2; ++i) {
    int c = i * 256 + tid;
    int v = c >> 3, s8 = (c & 7) * 8;
    short8 o;
#pragma unroll
    for (int e = 0; e < 8; ++e) o[e] = Tl[s8 + e][v];
    *(short8*)&kvT[((size_t)b * 512 + v0 + v) * SEQ + s0 + s8] = o;
  }
}

// ---------------- Flash attention v5 + T5 setprio (round-10/12/14 proven) ----------------
__global__ __launch_bounds__(512, 2) void attn3(
    const ushort* __restrict__ q_eff, const ushort* __restrict__ keff,
    const ushort* __restrict__ kvT, ushort* __restrict__ out_lat)
{
  const int pair = blockIdx.x;          // 0..7
  const int h = blockIdx.y, b = blockIdx.z;
  const int tid = threadIdx.x, lane = tid & 63, w = tid >> 6;
  __shared__ ushort Ks[2][32 * KSTR];   // 2 x 37888 B
  __shared__ ushort Vt[2][512 * 32];    // 2 x 32768 B, [v][key] stride 32
  __shared__ ushort Pl[8][16 * 40];     // 10240 B, per-wave P

  const int fr = lane & 15, g = lane >> 4;

  auto stageK = [&](int kt, int buf) {
    const ushort* ksrc = keff + ((size_t)b * SEQ + (size_t)kt * 32) * KSTR;
    ushort* kd = &Ks[buf][0];
#pragma unroll
    for (int i = 0; i < 5; ++i) {
      int c0 = w * 320 + i * 64;
      if (c0 < KCH) {
        int c = c0 + lane;
        gld_lds16(ksrc + (size_t)c * 8, (void*)(kd + (size_t)c * 8));
      }
    }
  };
  auto stageV = [&](int kt, int buf) {
    const ushort* vsrc = kvT + (size_t)b * 512 * SEQ + (size_t)kt * 32;
    ushort* vd = &Vt[buf][0];
#pragma unroll
    for (int i = 0; i < 4; ++i) {
      int c = w * 256 + i * 64 + lane;
      gld_lds16(vsrc + (size_t)(c >> 2) * SEQ + (c & 3) * 8, (void*)(vd + (size_t)c * 8));
    }
  };

  for (int half = 0; half < 2; ++half) {
    const int qb = half ? pair : (15 - pair);
    const int q0 = qb * 128 + w * 16;   // wave's first q row (in batch)

    const ushort* qrow = q_eff + ((size_t)h * T_TOK + (size_t)b * SEQ + q0 + fr) * DQK + g * 8;
    short8 qf[18];
#pragma unroll
    for (int ks = 0; ks < 18; ++ks) qf[ks] = *(const short8*)(qrow + ks * 32);

    f32x4 acc[32] = {};
    float m_s[4] = {-1e30f, -1e30f, -1e30f, -1e30f};
    float l_s[4] = {0.f, 0.f, 0.f, 0.f};

    const int nt = 4 * qb + 4;

    stageK(0, 0);
    stageV(0, 0);

    for (int kt = 0; kt < nt; ++kt) {
      const int cur = kt & 1;
      if (kt + 1 < nt) {
        stageK(kt + 1, cur ^ 1);
        stageV(kt + 1, cur ^ 1);
        if (w == 7) asm volatile("s_waitcnt vmcnt(6)" ::: "memory");
        else        asm volatile("s_waitcnt vmcnt(9)" ::: "memory");
      } else {
        asm volatile("s_waitcnt vmcnt(0)" ::: "memory");
      }
      __builtin_amdgcn_sched_barrier(0);
      __builtin_amdgcn_s_barrier();
      __builtin_amdgcn_sched_barrier(0);

      if (kt * 32 <= q0 + 15) {
        const ushort* Kc = &Ks[cur][0];
        const ushort* Vc = &Vt[cur][0];
        f32x4 s0 = {}, s1 = {};
        __builtin_amdgcn_s_setprio(1);
#pragma unroll
        for (int ks = 0; ks < 18; ++ks) {
          short8 b0 = *(const short8*)(Kc + (0 * 16 + fr) * KSTR + ks * 32 + g * 8);
          short8 b1 = *(const short8*)(Kc + (1 * 16 + fr) * KSTR + ks * 32 + g * 8);
          s0 = __builtin_amdgcn_mfma_f32_16x16x32_bf16(qf[ks], b0, s0, 0, 0, 0);
          s1 = __builtin_amdgcn_mfma_f32_16x16x32_bf16(qf[ks], b1, s1, 0, 0, 0);
        }
        __builtin_amdgcn_s_setprio(0);
        const float SC = 0.07216878364870322f;   // 1/sqrt(DN+DR=192)
        const bool diag = (kt * 32 + 31 > q0);
        float sv0[4], sv1[4];
#pragma unroll
        for (int r = 0; r < 4; ++r) {
          int qg = q0 + 4 * g + r;
          float a0 = s0[r] * SC, a1 = s1[r] * SC;
          if (diag) {
            if (kt * 32 + fr > qg)      a0 = -1e30f;
            if (kt * 32 + 16 + fr > qg) a1 = -1e30f;
          }
          sv0[r] = a0; sv1[r] = a1;
        }
        float mx[4];
#pragma unroll
        for (int r = 0; r < 4; ++r) {
          float m2 = fmaxf(sv0[r], sv1[r]);
          m2 = fmaxf(m2, __shfl_xor(m2, 1));
          m2 = fmaxf(m2, __shfl_xor(m2, 2));
          m2 = fmaxf(m2, __shfl_xor(m2, 4));
          m2 = fmaxf(m2, __shfl_xor(m2, 8));
          mx[r] = m2;
        }
        float need = mx[0] - m_s[0];
#pragma unroll
        for (int r = 1; r < 4; ++r) need = fmaxf(need, mx[r] - m_s[r]);
        if (__any(need > 8.0f)) {
          float rsc[4];
#pragma unroll
          for (int r = 0; r < 4; ++r) {
            float mn = fmaxf(m_s[r], mx[r]);
            rsc[r] = __expf(m_s[r] - mn);
            m_s[r] = mn;
            l_s[r] *= rsc[r];
          }
#pragma unroll
          for (int n2 = 0; n2 < 32; ++n2)
#pragma unroll
            for (int r = 0; r < 4; ++r) acc[n2][r] *= rsc[r];
        }
        float p0[4], p1[4];
#pragma unroll
        for (int r = 0; r < 4; ++r) {
          p0[r] = __expf(sv0[r] - m_s[r]);
          p1[r] = __expf(sv1[r] - m_s[r]);
          float ps = p0[r] + p1[r];
          ps += __shfl_xor(ps, 1);
          ps += __shfl_xor(ps, 2);
          ps += __shfl_xor(ps, 4);
          ps += __shfl_xor(ps, 8);
          l_s[r] += ps;
          Pl[w][(4 * g + r) * 40 + fr]      = f2bf(p0[r]);
          Pl[w][(4 * g + r) * 40 + 16 + fr] = f2bf(p1[r]);
        }
        short8 pa = *(const short8*)(Pl[w] + fr * 40 + g * 8);
        __builtin_amdgcn_s_setprio(1);
#pragma unroll
        for (int n2 = 0; n2 < 32; ++n2) {
          short8 bv = *(const short8*)(Vc + (n2 * 16 + fr) * 32 + g * 8);
          acc[n2] = __builtin_amdgcn_mfma_f32_16x16x32_bf16(pa, bv, acc[n2], 0, 0, 0);
        }
        __builtin_amdgcn_s_setprio(0);
      }
      __builtin_amdgcn_sched_barrier(0);
      __builtin_amdgcn_s_barrier();
      __builtin_amdgcn_sched_barrier(0);
    }

    const size_t obase = ((size_t)h * T_TOK + (size_t)b * SEQ + q0) * LAT;
    float inv[4];
#pragma unroll
    for (int r = 0; r < 4; ++r) inv[r] = 1.0f / l_s[r];
#pragma unroll
    for (int n2 = 0; n2 < 32; ++n2)
#pragma unroll
      for (int r = 0; r < 4; ++r)
        out_lat[obase + (size_t)(4 * g + r) * LAT + n2 * 16 + fr] = f2bf(acc[n2][r] * inv[r]);
  }
}

// ---------------- launch ----------------
extern "C" void kernel_launch(void* const* d_in, const int* in_sizes, int n_in,
                              void* d_out, int out_size, void* d_ws, size_t ws_size,
                              hipStream_t stream) {
  const float* hs   = (const float*)d_in[0];
  const float* cosb = (const float*)d_in[1];
  const float* sinb = (const float*)d_in[2];
  const float* qw   = (const float*)d_in[3];
  const float* kvw  = (const float*)d_in[4];
  const float* lnw  = (const float*)d_in[5];
  const float* wuk  = (const float*)d_in[6];
  const float* wuv  = (const float*)d_in[7];
  const float* wo   = (const float*)d_in[8];
  float* out = (float*)d_out;
  char* ws = (char*)d_ws;

  // workspace layout (bytes); out_lat aliases the region dead by attention time
  const size_t o_xb   = 0;              // 16,777,216
  const size_t o_qb   = 16777216;       // 4096x3712 bf16 = 30,408,704
  const size_t o_wq   = 47185920;       // 12,582,912
  const size_t o_wkv  = 59768832;       // 2,621,440 (contiguous after wq)
  const size_t o_ol   = 0;              // out_lat 67,108,864 (alias; above dead by attn)
  const size_t o_wukt = 67108864;       // 2,097,152
  const size_t o_wuvt = 69206016;       // 2,097,152
  const size_t o_wo   = 71303168;       // 8,388,608
  const size_t o_keff = 79691776;       // 4096x592 bf16 = 4,849,664
  const size_t o_qeff = 84541440;       // 16x4096x576 bf16 = 75,497,472
  const size_t o_oh   = 160038912;      // 16,777,216
  const size_t o_kvt  = 176816128;      // 4,194,304 -> ends 181,010,432

  ushort* xb    = (ushort*)(ws + o_xb);
  ushort* qbuf  = (ushort*)(ws + o_qb);
  ushort* wq_b  = (ushort*)(ws + o_wq);
  ushort* wkv_b = (ushort*)(ws + o_wkv);
  ushort* olat  = (ushort*)(ws + o_ol);
  ushort* wukt  = (ushort*)(ws + o_wukt);
  ushort* wuvt  = (ushort*)(ws + o_wuvt);
  ushort* wo_b  = (ushort*)(ws + o_wo);
  ushort* keff  = (ushort*)(ws + o_keff);
  ushort* qeff  = (ushort*)(ws + o_qeff);
  ushort* ohead = (ushort*)(ws + o_oh);
  ushort* kvt   = (ushort*)(ws + o_kvt);

  // 1) casts
  cast4<<<8192, 256, 0, stream>>>(hs, xb, 8388608 / 4);
  cast4<<<6144, 256, 0, stream>>>(qw, wq_b, 6291456 / 4);
  cast_pad_kv<<<1280, 256, 0, stream>>>(kvw, wkv_b);
  cast4<<<4096, 256, 0, stream>>>(wo, wo_b, 4194304 / 4);
  cast_wukv<<<8192, 256, 0, stream>>>(wuk, wuv, wukt, wuvt);

  // 2) [q | ckv] = x @ [q_proj_w ; kv_a_proj_w_padded]^T  (bf16 out, merged)
  gemm_bt<1><<<dim3(29, 32, 1), 256, 0, stream>>>(xb, wq_b, qbuf, 2048, 2048, 2048, QCKV, 0, 0, 0);
  // 3) RMSNorm + RoPE-k -> k_eff, and RoPE-q -> q_eff[., 512..576] (fused)
  rms_rope_kq<<<4096, 256, 0, stream>>>(qbuf, lnw, cosb, sinb, keff, qeff);
  // 3b) kvT = kv_c^T per batch
  transpose_kv<<<dim3(32, 8, 2), 256, 0, stream>>>(keff, kvt);
  // 4) q_lat per head -> q_eff[., 0..512]
  gemm_bt<1><<<dim3(4, 32, 16), 256, 0, stream>>>(qbuf, wukt, qeff, 128, QCKV, 128, 576,
                                                  192LL, 65536LL, 2359296LL);
  // 5) attention -> out_lat
  attn3<<<dim3(8, 16, 2), 512, 0, stream>>>(qeff, keff, kvt, olat);
  // 6) o_head = out_lat @ W_UV (per head)
  gemm_bt<1><<<dim3(1, 32, 16), 256, 0, stream>>>(olat, wuvt, ohead, 512, 512, 512, 2048,
                                                  2097152LL, 65536LL, 128LL);
  // 7) out = o_head @ o_proj_w^T (f32 out)
  gemm_bt<0><<<dim3(16, 32, 1), 256, 0, stream>>>(ohead, wo_b, out, 2048, 2048, 2048, 2048, 0, 0, 0);
}

// Round 16
// 614.834 us; speedup vs baseline: 1.1922x; 1.0063x over previous
//
#include <hip/hip_runtime.h>
#include <stdint.h>

// Problem constants
#define T_TOK 4096   // B*S
#define HIDD  2048
#define NH    16
#define DNN   128
#define DRR   64
#define DVV   128
#define LAT   512
#define DQK   576    // LAT + DR
#define SEQ   2048
#define NB    2
#define KSTR  592    // padded keff row stride (ushorts) = 74 chunks of 16B
#define KCH   2368   // 16B chunks per K tile (32*KSTR/8)
#define QCKV  3712   // merged q(3072) + ckv(640) row stride

typedef __attribute__((__ext_vector_type__(8))) short short8;
typedef __attribute__((__ext_vector_type__(4))) float f32x4;

__device__ __forceinline__ float bf2f(ushort u) {
  union { uint32_t i; float f; } v; v.i = ((uint32_t)u) << 16; return v.f;
}
__device__ __forceinline__ ushort f2bf(float f) {
  union { float f; uint32_t i; } v; v.f = f;
  uint32_t r = v.i + 0x7FFF + ((v.i >> 16) & 1);
  return (ushort)(r >> 16);
}

__device__ __forceinline__ void gld_lds16(const void* g, void* l) {
  __builtin_amdgcn_global_load_lds((const __attribute__((address_space(1))) void*)g,
                                   (__attribute__((address_space(3))) void*)l, 16, 0, 0);
}

// ---------------- cast kernels ----------------
__global__ void cast4(const float* __restrict__ in, ushort* __restrict__ out, int n4) {
  int i = blockIdx.x * blockDim.x + threadIdx.x;
  if (i >= n4) return;
  float4 v = ((const float4*)in)[i];
  ushort4 o; o.x = f2bf(v.x); o.y = f2bf(v.y); o.z = f2bf(v.z); o.w = f2bf(v.w);
  ((ushort4*)out)[i] = o;
}

// kv_a_proj_w (576x2048) -> padded (640x2048) bf16, pad rows zero
__global__ void cast_pad_kv(const float* __restrict__ in, ushort* __restrict__ out) {
  int i = blockIdx.x * 256 + threadIdx.x;     // over 640*2048/4
  int row = (i * 4) >> 11;
  ushort4 o;
  if (row < 576) {
    float4 v = ((const float4*)in)[i];
    o.x = f2bf(v.x); o.y = f2bf(v.y); o.z = f2bf(v.z); o.w = f2bf(v.w);
  } else { o.x = 0; o.y = 0; o.z = 0; o.w = 0; }
  ((ushort4*)out)[i] = o;
}

// merged weight casts:
//   blocks    0..4095  -> wuk_t[h][l][d] = W_UK_T[h][d][l]
//   blocks 4096..8191  -> wuv_t[h][v][l] = W_UV[h][l][v]
//   blocks 8192..12287 -> wo bf16 cast (vectorized)
__global__ void cast_wukv_wo(const float* __restrict__ wuk, const float* __restrict__ wuv,
                             const float* __restrict__ wo,
                             ushort* __restrict__ outk, ushort* __restrict__ outv,
                             ushort* __restrict__ outo) {
  if (blockIdx.x < 4096) {
    int o = blockIdx.x * 256 + threadIdx.x;   // 16*512*128
    int d = o & 127, l = (o >> 7) & 511, h = o >> 16;
    outk[o] = f2bf(wuk[((size_t)(h * 128 + d)) * 512 + l]);
  } else if (blockIdx.x < 8192) {
    int o = (blockIdx.x - 4096) * 256 + threadIdx.x;   // 16*128*512
    int l = o & 511, v = (o >> 9) & 127, h = o >> 16;
    outv[o] = f2bf(wuv[((size_t)(h * 512 + l)) * 128 + v]);
  } else {
    int i = (blockIdx.x - 8192) * 256 + threadIdx.x;   // over 2048*2048/4
    float4 v = ((const float4*)wo)[i];
    ushort4 o; o.x = f2bf(v.x); o.y = f2bf(v.y); o.z = f2bf(v.z); o.w = f2bf(v.w);
    ((ushort4*)outo)[i] = o;
  }
}

// ---------------- GEMM v3: dbuf LDS + counted vmcnt + XCD-bijective swizzle ----------------
template<int OUT_BF16>
__global__ __launch_bounds__(256) void gemm_bt(
    const ushort* __restrict__ A, const ushort* __restrict__ B, void* __restrict__ Cv,
    int K, int lda, int ldb, int ldc,
    long long aB, long long bB, long long cB)
{
  __shared__ ushort As[2][128 * 32];
  __shared__ ushort Bs[2][128 * 32];
  const int tid = threadIdx.x;
  const int lane = tid & 63, wid = tid >> 6;

  const int gx = gridDim.x;
  const int nwg = gx * gridDim.y;
  int l = blockIdx.y * gx + blockIdx.x;
  int tile = l;
  if ((nwg & 7) == 0) tile = (l & 7) * (nwg >> 3) + (l >> 3);
  const int m0 = (tile / gx) * 128, n0 = (tile % gx) * 128;

  A += (size_t)blockIdx.z * aB;
  B += (size_t)blockIdx.z * bB;
  const int wm = (wid >> 1) * 64, wn = (wid & 1) * 64;
  const int fr = lane & 15;
  const int kk = (lane >> 4) * 8;

  auto stage = [&](int k0, int buf) {
#pragma unroll
    for (int i = 0; i < 2; ++i) {
      int c = i * 256 + tid;
      gld_lds16(A + (size_t)(m0 + (c >> 2)) * lda + k0 + (c & 3) * 8, (void*)(&As[buf][0] + c * 8));
    }
#pragma unroll
    for (int i = 0; i < 2; ++i) {
      int c = i * 256 + tid;
      gld_lds16(B + (size_t)(n0 + (c >> 2)) * ldb + k0 + (c & 3) * 8, (void*)(&Bs[buf][0] + c * 8));
    }
  };

  f32x4 acc[4][4] = {};
  const int nt = K >> 5;
  stage(0, 0);
  for (int t = 0; t < nt; ++t) {
    const int cur = t & 1;
    if (t + 1 < nt) {
      stage((t + 1) << 5, cur ^ 1);
      asm volatile("s_waitcnt vmcnt(4)" ::: "memory");
    } else {
      asm volatile("s_waitcnt vmcnt(0)" ::: "memory");
    }
    __builtin_amdgcn_sched_barrier(0);
    __builtin_amdgcn_s_barrier();
    __builtin_amdgcn_sched_barrier(0);

    short8 af[4], bf[4];
#pragma unroll
    for (int x = 0; x < 4; ++x) af[x] = *(const short8*)(&As[cur][0] + (wm + x * 16 + fr) * 32 + kk);
#pragma unroll
    for (int x = 0; x < 4; ++x) bf[x] = *(const short8*)(&Bs[cur][0] + (wn + x * 16 + fr) * 32 + kk);
#pragma unroll
    for (int mi = 0; mi < 4; ++mi)
#pragma unroll
      for (int ni = 0; ni < 4; ++ni)
        acc[mi][ni] = __builtin_amdgcn_mfma_f32_16x16x32_bf16(af[mi], bf[ni], acc[mi][ni], 0, 0, 0);

    __builtin_amdgcn_sched_barrier(0);
    __builtin_amdgcn_s_barrier();
    __builtin_amdgcn_sched_barrier(0);
  }

  const int rb = (lane >> 4) * 4;
#pragma unroll
  for (int mi = 0; mi < 4; ++mi)
#pragma unroll
    for (int ni = 0; ni < 4; ++ni)
#pragma unroll
      for (int r = 0; r < 4; ++r) {
        size_t row = (size_t)(m0 + wm + mi * 16 + rb + r);
        size_t col = (size_t)(n0 + wn + ni * 16 + fr);
        size_t idx = row * (size_t)ldc + col + (size_t)blockIdx.z * cB;
        if (OUT_BF16) ((ushort*)Cv)[idx] = f2bf(acc[mi][ni][r]);
        else          ((float*)Cv)[idx]  = acc[mi][ni][r];
      }
}

// ---------------- GEMM specialization: K=128, all sub-tiles staged once, 1 barrier ----------------
// Faithful unroll of gemm_bt's loop: same staging primitive/layout, same fragment
// reads, same accumulator recipe, same epilogue. No inter-phase barriers needed
// because no LDS buffer is ever overwritten.
__global__ __launch_bounds__(256) void gemm_k128(
    const ushort* __restrict__ A, const ushort* __restrict__ B, ushort* __restrict__ C,
    int lda, int ldb, int ldc,
    long long aB, long long bB, long long cB)
{
  __shared__ ushort As[4][128 * 32];
  __shared__ ushort Bs[4][128 * 32];
  const int tid = threadIdx.x;
  const int lane = tid & 63, wid = tid >> 6;

  const int gx = gridDim.x;
  const int nwg = gx * gridDim.y;
  int l = blockIdx.y * gx + blockIdx.x;
  int tile = l;
  if ((nwg & 7) == 0) tile = (l & 7) * (nwg >> 3) + (l >> 3);
  const int m0 = (tile / gx) * 128, n0 = (tile % gx) * 128;

  A += (size_t)blockIdx.z * aB;
  B += (size_t)blockIdx.z * bB;
  const int wm = (wid >> 1) * 64, wn = (wid & 1) * 64;
  const int fr = lane & 15;
  const int kk = (lane >> 4) * 8;

#pragma unroll
  for (int kc = 0; kc < 4; ++kc) {
#pragma unroll
    for (int i = 0; i < 2; ++i) {
      int c = i * 256 + tid;
      gld_lds16(A + (size_t)(m0 + (c >> 2)) * lda + kc * 32 + (c & 3) * 8, (void*)(&As[kc][0] + c * 8));
    }
#pragma unroll
    for (int i = 0; i < 2; ++i) {
      int c = i * 256 + tid;
      gld_lds16(B + (size_t)(n0 + (c >> 2)) * ldb + kc * 32 + (c & 3) * 8, (void*)(&Bs[kc][0] + c * 8));
    }
  }
  asm volatile("s_waitcnt vmcnt(0)" ::: "memory");
  __builtin_amdgcn_sched_barrier(0);
  __builtin_amdgcn_s_barrier();
  __builtin_amdgcn_sched_barrier(0);

  f32x4 acc[4][4] = {};
#pragma unroll
  for (int kc = 0; kc < 4; ++kc) {
    short8 af[4], bf[4];
#pragma unroll
    for (int x = 0; x < 4; ++x) af[x] = *(const short8*)(&As[kc][0] + (wm + x * 16 + fr) * 32 + kk);
#pragma unroll
    for (int x = 0; x < 4; ++x) bf[x] = *(const short8*)(&Bs[kc][0] + (wn + x * 16 + fr) * 32 + kk);
#pragma unroll
    for (int mi = 0; mi < 4; ++mi)
#pragma unroll
      for (int ni = 0; ni < 4; ++ni)
        acc[mi][ni] = __builtin_amdgcn_mfma_f32_16x16x32_bf16(af[mi], bf[ni], acc[mi][ni], 0, 0, 0);
  }

  const int rb = (lane >> 4) * 4;
#pragma unroll
  for (int mi = 0; mi < 4; ++mi)
#pragma unroll
    for (int ni = 0; ni < 4; ++ni)
#pragma unroll
      for (int r = 0; r < 4; ++r) {
        size_t row = (size_t)(m0 + wm + mi * 16 + rb + r);
        size_t col = (size_t)(n0 + wn + ni * 16 + fr);
        C[row * (size_t)ldc + col + (size_t)blockIdx.z * cB] = f2bf(acc[mi][ni][r]);
      }
}

// ---------------- RMSNorm + RoPE-k + RoPE-q (fused, one block per token) ----------------
__global__ __launch_bounds__(256) void rms_rope_kq(
    const ushort* __restrict__ qckv, const float* __restrict__ lnw,
    const float* __restrict__ cosb, const float* __restrict__ sinb,
    ushort* __restrict__ k_eff, ushort* __restrict__ q_eff)
{
  const int t = blockIdx.x, tid = threadIdx.x;
  __shared__ float red[4];
  const size_t base = (size_t)t * QCKV + 3072;
  float v0 = bf2f(qckv[base + tid]);
  float v1 = bf2f(qckv[base + 256 + tid]);
  float ss = v0 * v0 + v1 * v1;
#pragma unroll
  for (int m = 1; m < 64; m <<= 1) ss += __shfl_xor(ss, m);
  if ((tid & 63) == 0) red[tid >> 6] = ss;

  // ---- RoPE-q (independent of the reduction): 16 heads x 64 dims = 4 items/thread ----
#pragma unroll
  for (int i = 0; i < 4; ++i) {
    int item = i * 256 + tid;           // 0..1023
    int hh = item >> 6, j = item & 63;
    size_t qb = (size_t)t * QCKV + hh * 192 + 128;
    int src  = (j < 32) ? 2 * j : 2 * (j - 32) + 1;
    int psrc = (j < 32) ? src + 1 : src - 1;
    float xv = bf2f(qckv[qb + src]), pv = bf2f(qckv[qb + psrc]);
    float c = cosb[t * 64 + j], s = sinb[t * 64 + j];
    q_eff[((size_t)hh * T_TOK + t) * DQK + 512 + j] = f2bf((j < 32) ? xv * c - pv * s : xv * c + pv * s);
  }

  __syncthreads();
  float rn = rsqrtf((red[0] + red[1] + red[2] + red[3]) * (1.0f / 512.0f) + 1e-6f);
  k_eff[(size_t)t * KSTR + tid]       = f2bf(v0 * rn * lnw[tid]);
  k_eff[(size_t)t * KSTR + 256 + tid] = f2bf(v1 * rn * lnw[256 + tid]);
  if (tid < 64) {
    int j = tid;
    int src  = (j < 32) ? 2 * j : 2 * (j - 32) + 1;
    int psrc = (j < 32) ? src + 1 : src - 1;
    float xv = bf2f(qckv[base + 512 + src]);
    float pv = bf2f(qckv[base + 512 + psrc]);
    float c = cosb[t * 64 + j], s = sinb[t * 64 + j];
    k_eff[(size_t)t * KSTR + 512 + j] = f2bf((j < 32) ? xv * c - pv * s : xv * c + pv * s);
  }
}

// ---------------- kvT[b][v][s] = kv_c[b][s][v] (64x64 LDS tiles) ----------------
__global__ __launch_bounds__(256) void transpose_kv(
    const ushort* __restrict__ keff, ushort* __restrict__ kvT)
{
  __shared__ ushort Tl[64][72];
  const int s0 = blockIdx.x * 64, v0 = blockIdx.y * 64, b = blockIdx.z;
  const int tid = threadIdx.x;
#pragma unroll
  for (int i = 0; i < 2; ++i) {
    int c = i * 256 + tid;
    int r = c >> 3, c8 = (c & 7) * 8;
    *(short8*)&Tl[r][c8] = *(const short8*)&keff[((size_t)b * SEQ + s0 + r) * KSTR + v0 + c8];
  }
  __syncthreads();
#pragma unroll
  for (int i = 0; i < 2; ++i) {
    int c = i * 256 + tid;
    int v = c >> 3, s8 = (c & 7) * 8;
    short8 o;
#pragma unroll
    for (int e = 0; e < 8; ++e) o[e] = Tl[s8 + e][v];
    *(short8*)&kvT[((size_t)b * 512 + v0 + v) * SEQ + s0 + s8] = o;
  }
}

// ---------------- Flash attention v5 + T5 setprio (round-10/12/14/15 proven) ----------------
__global__ __launch_bounds__(512, 2) void attn3(
    const ushort* __restrict__ q_eff, const ushort* __restrict__ keff,
    const ushort* __restrict__ kvT, ushort* __restrict__ out_lat)
{
  const int pair = blockIdx.x;          // 0..7
  const int h = blockIdx.y, b = blockIdx.z;
  const int tid = threadIdx.x, lane = tid & 63, w = tid >> 6;
  __shared__ ushort Ks[2][32 * KSTR];   // 2 x 37888 B
  __shared__ ushort Vt[2][512 * 32];    // 2 x 32768 B, [v][key] stride 32
  __shared__ ushort Pl[8][16 * 40];     // 10240 B, per-wave P

  const int fr = lane & 15, g = lane >> 4;

  auto stageK = [&](int kt, int buf) {
    const ushort* ksrc = keff + ((size_t)b * SEQ + (size_t)kt * 32) * KSTR;
    ushort* kd = &Ks[buf][0];
#pragma unroll
    for (int i = 0; i < 5; ++i) {
      int c0 = w * 320 + i * 64;
      if (c0 < KCH) {
        int c = c0 + lane;
        gld_lds16(ksrc + (size_t)c * 8, (void*)(kd + (size_t)c * 8));
      }
    }
  };
  auto stageV = [&](int kt, int buf) {
    const ushort* vsrc = kvT + (size_t)b * 512 * SEQ + (size_t)kt * 32;
    ushort* vd = &Vt[buf][0];
#pragma unroll
    for (int i = 0; i < 4; ++i) {
      int c = w * 256 + i * 64 + lane;
      gld_lds16(vsrc + (size_t)(c >> 2) * SEQ + (c & 3) * 8, (void*)(vd + (size_t)c * 8));
    }
  };

  for (int half = 0; half < 2; ++half) {
    const int qb = half ? pair : (15 - pair);
    const int q0 = qb * 128 + w * 16;   // wave's first q row (in batch)

    const ushort* qrow = q_eff + ((size_t)h * T_TOK + (size_t)b * SEQ + q0 + fr) * DQK + g * 8;
    short8 qf[18];
#pragma unroll
    for (int ks = 0; ks < 18; ++ks) qf[ks] = *(const short8*)(qrow + ks * 32);

    f32x4 acc[32] = {};
    float m_s[4] = {-1e30f, -1e30f, -1e30f, -1e30f};
    float l_s[4] = {0.f, 0.f, 0.f, 0.f};

    const int nt = 4 * qb + 4;

    stageK(0, 0);
    stageV(0, 0);

    for (int kt = 0; kt < nt; ++kt) {
      const int cur = kt & 1;
      if (kt + 1 < nt) {
        stageK(kt + 1, cur ^ 1);
        stageV(kt + 1, cur ^ 1);
        if (w == 7) asm volatile("s_waitcnt vmcnt(6)" ::: "memory");
        else        asm volatile("s_waitcnt vmcnt(9)" ::: "memory");
      } else {
        asm volatile("s_waitcnt vmcnt(0)" ::: "memory");
      }
      __builtin_amdgcn_sched_barrier(0);
      __builtin_amdgcn_s_barrier();
      __builtin_amdgcn_sched_barrier(0);

      if (kt * 32 <= q0 + 15) {
        const ushort* Kc = &Ks[cur][0];
        const ushort* Vc = &Vt[cur][0];
        f32x4 s0 = {}, s1 = {};
        __builtin_amdgcn_s_setprio(1);
#pragma unroll
        for (int ks = 0; ks < 18; ++ks) {
          short8 b0 = *(const short8*)(Kc + (0 * 16 + fr) * KSTR + ks * 32 + g * 8);
          short8 b1 = *(const short8*)(Kc + (1 * 16 + fr) * KSTR + ks * 32 + g * 8);
          s0 = __builtin_amdgcn_mfma_f32_16x16x32_bf16(qf[ks], b0, s0, 0, 0, 0);
          s1 = __builtin_amdgcn_mfma_f32_16x16x32_bf16(qf[ks], b1, s1, 0, 0, 0);
        }
        __builtin_amdgcn_s_setprio(0);
        const float SC = 0.07216878364870322f;   // 1/sqrt(DN+DR=192)
        const bool diag = (kt * 32 + 31 > q0);
        float sv0[4], sv1[4];
#pragma unroll
        for (int r = 0; r < 4; ++r) {
          int qg = q0 + 4 * g + r;
          float a0 = s0[r] * SC, a1 = s1[r] * SC;
          if (diag) {
            if (kt * 32 + fr > qg)      a0 = -1e30f;
            if (kt * 32 + 16 + fr > qg) a1 = -1e30f;
          }
          sv0[r] = a0; sv1[r] = a1;
        }
        float mx[4];
#pragma unroll
        for (int r = 0; r < 4; ++r) {
          float m2 = fmaxf(sv0[r], sv1[r]);
          m2 = fmaxf(m2, __shfl_xor(m2, 1));
          m2 = fmaxf(m2, __shfl_xor(m2, 2));
          m2 = fmaxf(m2, __shfl_xor(m2, 4));
          m2 = fmaxf(m2, __shfl_xor(m2, 8));
          mx[r] = m2;
        }
        float need = mx[0] - m_s[0];
#pragma unroll
        for (int r = 1; r < 4; ++r) need = fmaxf(need, mx[r] - m_s[r]);
        if (__any(need > 8.0f)) {
          float rsc[4];
#pragma unroll
          for (int r = 0; r < 4; ++r) {
            float mn = fmaxf(m_s[r], mx[r]);
            rsc[r] = __expf(m_s[r] - mn);
            m_s[r] = mn;
            l_s[r] *= rsc[r];
          }
#pragma unroll
          for (int n2 = 0; n2 < 32; ++n2)
#pragma unroll
            for (int r = 0; r < 4; ++r) acc[n2][r] *= rsc[r];
        }
        float p0[4], p1[4];
#pragma unroll
        for (int r = 0; r < 4; ++r) {
          p0[r] = __expf(sv0[r] - m_s[r]);
          p1[r] = __expf(sv1[r] - m_s[r]);
          float ps = p0[r] + p1[r];
          ps += __shfl_xor(ps, 1);
          ps += __shfl_xor(ps, 2);
          ps += __shfl_xor(ps, 4);
          ps += __shfl_xor(ps, 8);
          l_s[r] += ps;
          Pl[w][(4 * g + r) * 40 + fr]      = f2bf(p0[r]);
          Pl[w][(4 * g + r) * 40 + 16 + fr] = f2bf(p1[r]);
        }
        short8 pa = *(const short8*)(Pl[w] + fr * 40 + g * 8);
        __builtin_amdgcn_s_setprio(1);
#pragma unroll
        for (int n2 = 0; n2 < 32; ++n2) {
          short8 bv = *(const short8*)(Vc + (n2 * 16 + fr) * 32 + g * 8);
          acc[n2] = __builtin_amdgcn_mfma_f32_16x16x32_bf16(pa, bv, acc[n2], 0, 0, 0);
        }
        __builtin_amdgcn_s_setprio(0);
      }
      __builtin_amdgcn_sched_barrier(0);
      __builtin_amdgcn_s_barrier();
      __builtin_amdgcn_sched_barrier(0);
    }

    const size_t obase = ((size_t)h * T_TOK + (size_t)b * SEQ + q0) * LAT;
    float inv[4];
#pragma unroll
    for (int r = 0; r < 4; ++r) inv[r] = 1.0f / l_s[r];
#pragma unroll
    for (int n2 = 0; n2 < 32; ++n2)
#pragma unroll
      for (int r = 0; r < 4; ++r)
        out_lat[obase + (size_t)(4 * g + r) * LAT + n2 * 16 + fr] = f2bf(acc[n2][r] * inv[r]);
  }
}

// ---------------- launch ----------------
extern "C" void kernel_launch(void* const* d_in, const int* in_sizes, int n_in,
                              void* d_out, int out_size, void* d_ws, size_t ws_size,
                              hipStream_t stream) {
  const float* hs   = (const float*)d_in[0];
  const float* cosb = (const float*)d_in[1];
  const float* sinb = (const float*)d_in[2];
  const float* qw   = (const float*)d_in[3];
  const float* kvw  = (const float*)d_in[4];
  const float* lnw  = (const float*)d_in[5];
  const float* wuk  = (const float*)d_in[6];
  const float* wuv  = (const float*)d_in[7];
  const float* wo   = (const float*)d_in[8];
  float* out = (float*)d_out;
  char* ws = (char*)d_ws;

  // workspace layout (bytes); out_lat aliases the region dead by attention time
  const size_t o_xb   = 0;              // 16,777,216
  const size_t o_qb   = 16777216;       // 4096x3712 bf16 = 30,408,704
  const size_t o_wq   = 47185920;       // 12,582,912
  const size_t o_wkv  = 59768832;       // 2,621,440 (contiguous after wq)
  const size_t o_ol   = 0;              // out_lat 67,108,864 (alias; above dead by attn)
  const size_t o_wukt = 67108864;       // 2,097,152
  const size_t o_wuvt = 69206016;       // 2,097,152
  const size_t o_wo   = 71303168;       // 8,388,608
  const size_t o_keff = 79691776;       // 4096x592 bf16 = 4,849,664
  const size_t o_qeff = 84541440;       // 16x4096x576 bf16 = 75,497,472
  const size_t o_oh   = 160038912;      // 16,777,216
  const size_t o_kvt  = 176816128;      // 4,194,304 -> ends 181,010,432

  ushort* xb    = (ushort*)(ws + o_xb);
  ushort* qbuf  = (ushort*)(ws + o_qb);
  ushort* wq_b  = (ushort*)(ws + o_wq);
  ushort* wkv_b = (ushort*)(ws + o_wkv);
  ushort* olat  = (ushort*)(ws + o_ol);
  ushort* wukt  = (ushort*)(ws + o_wukt);
  ushort* wuvt  = (ushort*)(ws + o_wuvt);
  ushort* wo_b  = (ushort*)(ws + o_wo);
  ushort* keff  = (ushort*)(ws + o_keff);
  ushort* qeff  = (ushort*)(ws + o_qeff);
  ushort* ohead = (ushort*)(ws + o_oh);
  ushort* kvt   = (ushort*)(ws + o_kvt);

  // 1) casts
  cast4<<<8192, 256, 0, stream>>>(hs, xb, 8388608 / 4);
  cast4<<<6144, 256, 0, stream>>>(qw, wq_b, 6291456 / 4);
  cast_pad_kv<<<1280, 256, 0, stream>>>(kvw, wkv_b);
  cast_wukv_wo<<<12288, 256, 0, stream>>>(wuk, wuv, wo, wukt, wuvt, wo_b);

  // 2) [q | ckv] = x @ [q_proj_w ; kv_a_proj_w_padded]^T  (bf16 out, merged)
  gemm_bt<1><<<dim3(29, 32, 1), 256, 0, stream>>>(xb, wq_b, qbuf, 2048, 2048, 2048, QCKV, 0, 0, 0);
  // 3) RMSNorm + RoPE-k -> k_eff, and RoPE-q -> q_eff[., 512..576] (fused)
  rms_rope_kq<<<4096, 256, 0, stream>>>(qbuf, lnw, cosb, sinb, keff, qeff);
  // 3b) kvT = kv_c^T per batch
  transpose_kv<<<dim3(32, 8, 2), 256, 0, stream>>>(keff, kvt);
  // 4) q_lat per head -> q_eff[., 0..512]  (K=128 single-stage GEMM)
  gemm_k128<<<dim3(4, 32, 16), 256, 0, stream>>>(qbuf, wukt, qeff, QCKV, 128, 576,
                                                 192LL, 65536LL, 2359296LL);
  // 5) attention -> out_lat
  attn3<<<dim3(8, 16, 2), 512, 0, stream>>>(qeff, keff, kvt, olat);
  // 6) o_head = out_lat @ W_UV (per head)
  gemm_bt<1><<<dim3(1, 32, 16), 256, 0, stream>>>(olat, wuvt, ohead, 512, 512, 512, 2048,
                                                  2097152LL, 65536LL, 128LL);
  // 7) out = o_head @ o_proj_w^T (f32 out)
  gemm_bt<0><<<dim3(16, 32, 1), 256, 0, stream>>>(ohead, wo_b, out, 2048, 2048, 2048, 2048, 0, 0, 0);
}

// Round 17
// 606.901 us; speedup vs baseline: 1.2078x; 1.0131x over previous
//
#include <hip/hip_runtime.h>
#include <stdint.h>

// Problem constants
#define T_TOK 4096   // B*S
#define HIDD  2048
#define NH    16
#define DNN   128
#define DRR   64
#define DVV   128
#define LAT   512
#define DQK   576    // LAT + DR
#define SEQ   2048
#define NB    2
#define KSTR  592    // padded keff row stride (ushorts) = 74 chunks of 16B
#define KCH   2368   // 16B chunks per K tile (32*KSTR/8)
#define QCKV  3712   // merged q(3072) + ckv(640) row stride

typedef __attribute__((__ext_vector_type__(8))) short short8;
typedef __attribute__((__ext_vector_type__(4))) float f32x4;

__device__ __forceinline__ float bf2f(ushort u) {
  union { uint32_t i; float f; } v; v.i = ((uint32_t)u) << 16; return v.f;
}
__device__ __forceinline__ ushort f2bf(float f) {
  union { float f; uint32_t i; } v; v.f = f;
  uint32_t r = v.i + 0x7FFF + ((v.i >> 16) & 1);
  return (ushort)(r >> 16);
}

__device__ __forceinline__ void gld_lds16(const void* g, void* l) {
  __builtin_amdgcn_global_load_lds((const __attribute__((address_space(1))) void*)g,
                                   (__attribute__((address_space(3))) void*)l, 16, 0, 0);
}

// ---------------- single merged cast kernel ----------------
// block ranges:
//   [0,     8192) : hs f32 -> bf16 (vectorized)      2097152 float4 items
//   [8192, 14336) : qw f32 -> bf16 (vectorized)      1572864 items
//   [14336,15616) : kv_a_proj_w -> padded 640x2048   327680 items
//   [15616,19712) : wuk_t[h][l][d] = W_UK_T[h][d][l]
//   [19712,23808) : wuv_t[h][v][l] = W_UV[h][l][v]
//   [23808,27904) : wo f32 -> bf16 (vectorized)      1048576 items
__global__ void cast_all(const float* __restrict__ hs, const float* __restrict__ qw,
                         const float* __restrict__ kvw, const float* __restrict__ wuk,
                         const float* __restrict__ wuv, const float* __restrict__ wo,
                         ushort* __restrict__ xb, ushort* __restrict__ wq_b,
                         ushort* __restrict__ wkv_b, ushort* __restrict__ outk,
                         ushort* __restrict__ outv, ushort* __restrict__ outo) {
  const int bx = blockIdx.x;
  if (bx < 8192) {
    int i = bx * 256 + threadIdx.x;
    float4 v = ((const float4*)hs)[i];
    ushort4 o; o.x = f2bf(v.x); o.y = f2bf(v.y); o.z = f2bf(v.z); o.w = f2bf(v.w);
    ((ushort4*)xb)[i] = o;
  } else if (bx < 14336) {
    int i = (bx - 8192) * 256 + threadIdx.x;
    float4 v = ((const float4*)qw)[i];
    ushort4 o; o.x = f2bf(v.x); o.y = f2bf(v.y); o.z = f2bf(v.z); o.w = f2bf(v.w);
    ((ushort4*)wq_b)[i] = o;
  } else if (bx < 15616) {
    int i = (bx - 14336) * 256 + threadIdx.x;   // over 640*2048/4
    int row = (i * 4) >> 11;
    ushort4 o;
    if (row < 576) {
      float4 v = ((const float4*)kvw)[i];
      o.x = f2bf(v.x); o.y = f2bf(v.y); o.z = f2bf(v.z); o.w = f2bf(v.w);
    } else { o.x = 0; o.y = 0; o.z = 0; o.w = 0; }
    ((ushort4*)wkv_b)[i] = o;
  } else if (bx < 19712) {
    int o = (bx - 15616) * 256 + threadIdx.x;   // 16*512*128
    int d = o & 127, l = (o >> 7) & 511, h = o >> 16;
    outk[o] = f2bf(wuk[((size_t)(h * 128 + d)) * 512 + l]);
  } else if (bx < 23808) {
    int o = (bx - 19712) * 256 + threadIdx.x;   // 16*128*512
    int l = o & 511, v = (o >> 9) & 127, h = o >> 16;
    outv[o] = f2bf(wuv[((size_t)(h * 512 + l)) * 128 + v]);
  } else {
    int i = (bx - 23808) * 256 + threadIdx.x;   // over 2048*2048/4
    float4 v = ((const float4*)wo)[i];
    ushort4 o; o.x = f2bf(v.x); o.y = f2bf(v.y); o.z = f2bf(v.z); o.w = f2bf(v.w);
    ((ushort4*)outo)[i] = o;
  }
}

// ---------------- GEMM v3: dbuf LDS + counted vmcnt + XCD-bijective swizzle ----------------
template<int OUT_BF16>
__global__ __launch_bounds__(256) void gemm_bt(
    const ushort* __restrict__ A, const ushort* __restrict__ B, void* __restrict__ Cv,
    int K, int lda, int ldb, int ldc,
    long long aB, long long bB, long long cB)
{
  __shared__ ushort As[2][128 * 32];
  __shared__ ushort Bs[2][128 * 32];
  const int tid = threadIdx.x;
  const int lane = tid & 63, wid = tid >> 6;

  const int gx = gridDim.x;
  const int nwg = gx * gridDim.y;
  int l = blockIdx.y * gx + blockIdx.x;
  int tile = l;
  if ((nwg & 7) == 0) tile = (l & 7) * (nwg >> 3) + (l >> 3);
  const int m0 = (tile / gx) * 128, n0 = (tile % gx) * 128;

  A += (size_t)blockIdx.z * aB;
  B += (size_t)blockIdx.z * bB;
  const int wm = (wid >> 1) * 64, wn = (wid & 1) * 64;
  const int fr = lane & 15;
  const int kk = (lane >> 4) * 8;

  auto stage = [&](int k0, int buf) {
#pragma unroll
    for (int i = 0; i < 2; ++i) {
      int c = i * 256 + tid;
      gld_lds16(A + (size_t)(m0 + (c >> 2)) * lda + k0 + (c & 3) * 8, (void*)(&As[buf][0] + c * 8));
    }
#pragma unroll
    for (int i = 0; i < 2; ++i) {
      int c = i * 256 + tid;
      gld_lds16(B + (size_t)(n0 + (c >> 2)) * ldb + k0 + (c & 3) * 8, (void*)(&Bs[buf][0] + c * 8));
    }
  };

  f32x4 acc[4][4] = {};
  const int nt = K >> 5;
  stage(0, 0);
  for (int t = 0; t < nt; ++t) {
    const int cur = t & 1;
    if (t + 1 < nt) {
      stage((t + 1) << 5, cur ^ 1);
      asm volatile("s_waitcnt vmcnt(4)" ::: "memory");
    } else {
      asm volatile("s_waitcnt vmcnt(0)" ::: "memory");
    }
    __builtin_amdgcn_sched_barrier(0);
    __builtin_amdgcn_s_barrier();
    __builtin_amdgcn_sched_barrier(0);

    short8 af[4], bf[4];
#pragma unroll
    for (int x = 0; x < 4; ++x) af[x] = *(const short8*)(&As[cur][0] + (wm + x * 16 + fr) * 32 + kk);
#pragma unroll
    for (int x = 0; x < 4; ++x) bf[x] = *(const short8*)(&Bs[cur][0] + (wn + x * 16 + fr) * 32 + kk);
#pragma unroll
    for (int mi = 0; mi < 4; ++mi)
#pragma unroll
      for (int ni = 0; ni < 4; ++ni)
        acc[mi][ni] = __builtin_amdgcn_mfma_f32_16x16x32_bf16(af[mi], bf[ni], acc[mi][ni], 0, 0, 0);

    __builtin_amdgcn_sched_barrier(0);
    __builtin_amdgcn_s_barrier();
    __builtin_amdgcn_sched_barrier(0);
  }

  const int rb = (lane >> 4) * 4;
#pragma unroll
  for (int mi = 0; mi < 4; ++mi)
#pragma unroll
    for (int ni = 0; ni < 4; ++ni)
#pragma unroll
      for (int r = 0; r < 4; ++r) {
        size_t row = (size_t)(m0 + wm + mi * 16 + rb + r);
        size_t col = (size_t)(n0 + wn + ni * 16 + fr);
        size_t idx = row * (size_t)ldc + col + (size_t)blockIdx.z * cB;
        if (OUT_BF16) ((ushort*)Cv)[idx] = f2bf(acc[mi][ni][r]);
        else          ((float*)Cv)[idx]  = acc[mi][ni][r];
      }
}

// ---------------- GEMM specialization: K=128, all sub-tiles staged once, 1 barrier ----------------
__global__ __launch_bounds__(256) void gemm_k128(
    const ushort* __restrict__ A, const ushort* __restrict__ B, ushort* __restrict__ C,
    int lda, int ldb, int ldc,
    long long aB, long long bB, long long cB)
{
  __shared__ ushort As[4][128 * 32];
  __shared__ ushort Bs[4][128 * 32];
  const int tid = threadIdx.x;
  const int lane = tid & 63, wid = tid >> 6;

  const int gx = gridDim.x;
  const int nwg = gx * gridDim.y;
  int l = blockIdx.y * gx + blockIdx.x;
  int tile = l;
  if ((nwg & 7) == 0) tile = (l & 7) * (nwg >> 3) + (l >> 3);
  const int m0 = (tile / gx) * 128, n0 = (tile % gx) * 128;

  A += (size_t)blockIdx.z * aB;
  B += (size_t)blockIdx.z * bB;
  const int wm = (wid >> 1) * 64, wn = (wid & 1) * 64;
  const int fr = lane & 15;
  const int kk = (lane >> 4) * 8;

#pragma unroll
  for (int kc = 0; kc < 4; ++kc) {
#pragma unroll
    for (int i = 0; i < 2; ++i) {
      int c = i * 256 + tid;
      gld_lds16(A + (size_t)(m0 + (c >> 2)) * lda + kc * 32 + (c & 3) * 8, (void*)(&As[kc][0] + c * 8));
    }
#pragma unroll
    for (int i = 0; i < 2; ++i) {
      int c = i * 256 + tid;
      gld_lds16(B + (size_t)(n0 + (c >> 2)) * ldb + kc * 32 + (c & 3) * 8, (void*)(&Bs[kc][0] + c * 8));
    }
  }
  asm volatile("s_waitcnt vmcnt(0)" ::: "memory");
  __builtin_amdgcn_sched_barrier(0);
  __builtin_amdgcn_s_barrier();
  __builtin_amdgcn_sched_barrier(0);

  f32x4 acc[4][4] = {};
#pragma unroll
  for (int kc = 0; kc < 4; ++kc) {
    short8 af[4], bf[4];
#pragma unroll
    for (int x = 0; x < 4; ++x) af[x] = *(const short8*)(&As[kc][0] + (wm + x * 16 + fr) * 32 + kk);
#pragma unroll
    for (int x = 0; x < 4; ++x) bf[x] = *(const short8*)(&Bs[kc][0] + (wn + x * 16 + fr) * 32 + kk);
#pragma unroll
    for (int mi = 0; mi < 4; ++mi)
#pragma unroll
      for (int ni = 0; ni < 4; ++ni)
        acc[mi][ni] = __builtin_amdgcn_mfma_f32_16x16x32_bf16(af[mi], bf[ni], acc[mi][ni], 0, 0, 0);
  }

  const int rb = (lane >> 4) * 4;
#pragma unroll
  for (int mi = 0; mi < 4; ++mi)
#pragma unroll
    for (int ni = 0; ni < 4; ++ni)
#pragma unroll
      for (int r = 0; r < 4; ++r) {
        size_t row = (size_t)(m0 + wm + mi * 16 + rb + r);
        size_t col = (size_t)(n0 + wn + ni * 16 + fr);
        C[row * (size_t)ldc + col + (size_t)blockIdx.z * cB] = f2bf(acc[mi][ni][r]);
      }
}

// ---------------- RMSNorm + RoPE-k + RoPE-q (fused, one block per token) ----------------
__global__ __launch_bounds__(256) void rms_rope_kq(
    const ushort* __restrict__ qckv, const float* __restrict__ lnw,
    const float* __restrict__ cosb, const float* __restrict__ sinb,
    ushort* __restrict__ k_eff, ushort* __restrict__ q_eff)
{
  const int t = blockIdx.x, tid = threadIdx.x;
  __shared__ float red[4];
  const size_t base = (size_t)t * QCKV + 3072;
  float v0 = bf2f(qckv[base + tid]);
  float v1 = bf2f(qckv[base + 256 + tid]);
  float ss = v0 * v0 + v1 * v1;
#pragma unroll
  for (int m = 1; m < 64; m <<= 1) ss += __shfl_xor(ss, m);
  if ((tid & 63) == 0) red[tid >> 6] = ss;

  // ---- RoPE-q (independent of the reduction): 16 heads x 64 dims = 4 items/thread ----
#pragma unroll
  for (int i = 0; i < 4; ++i) {
    int item = i * 256 + tid;           // 0..1023
    int hh = item >> 6, j = item & 63;
    size_t qb = (size_t)t * QCKV + hh * 192 + 128;
    int src  = (j < 32) ? 2 * j : 2 * (j - 32) + 1;
    int psrc = (j < 32) ? src + 1 : src - 1;
    float xv = bf2f(qckv[qb + src]), pv = bf2f(qckv[qb + psrc]);
    float c = cosb[t * 64 + j], s = sinb[t * 64 + j];
    q_eff[((size_t)hh * T_TOK + t) * DQK + 512 + j] = f2bf((j < 32) ? xv * c - pv * s : xv * c + pv * s);
  }

  __syncthreads();
  float rn = rsqrtf((red[0] + red[1] + red[2] + red[3]) * (1.0f / 512.0f) + 1e-6f);
  k_eff[(size_t)t * KSTR + tid]       = f2bf(v0 * rn * lnw[tid]);
  k_eff[(size_t)t * KSTR + 256 + tid] = f2bf(v1 * rn * lnw[256 + tid]);
  if (tid < 64) {
    int j = tid;
    int src  = (j < 32) ? 2 * j : 2 * (j - 32) + 1;
    int psrc = (j < 32) ? src + 1 : src - 1;
    float xv = bf2f(qckv[base + 512 + src]);
    float pv = bf2f(qckv[base + 512 + psrc]);
    float c = cosb[t * 64 + j], s = sinb[t * 64 + j];
    k_eff[(size_t)t * KSTR + 512 + j] = f2bf((j < 32) ? xv * c - pv * s : xv * c + pv * s);
  }
}

// ---------------- kvT[b][v][s] = kv_c[b][s][v] (64x64 LDS tiles) ----------------
__global__ __launch_bounds__(256) void transpose_kv(
    const ushort* __restrict__ keff, ushort* __restrict__ kvT)
{
  __shared__ ushort Tl[64][72];
  const int s0 = blockIdx.x * 64, v0 = blockIdx.y * 64, b = blockIdx.z;
  const int tid = threadIdx.x;
#pragma unroll
  for (int i = 0; i < 2; ++i) {
    int c = i * 256 + tid;
    int r = c >> 3, c8 = (c & 7) * 8;
    *(short8*)&Tl[r][c8] = *(const short8*)&keff[((size_t)b * SEQ + s0 + r) * KSTR + v0 + c8];
  }
  __syncthreads();
#pragma unroll
  for (int i = 0; i < 2; ++i) {
    int c = i * 256 + tid;
    int v = c >> 3, s8 = (c & 7) * 8;
    short8 o;
#pragma unroll
    for (int e = 0; e < 8; ++e) o[e] = Tl[s8 + e][v];
    *(short8*)&kvT[((size_t)b * 512 + v0 + v) * SEQ + s0 + s8] = o;
  }
}

// ---------------- Flash attention v5 + T5 setprio (round-10..16 proven) ----------------
__global__ __launch_bounds__(512, 2) void attn3(
    const ushort* __restrict__ q_eff, const ushort* __restrict__ keff,
    const ushort* __restrict__ kvT, ushort* __restrict__ out_lat)
{
  const int pair = blockIdx.x;          // 0..7
  const int h = blockIdx.y, b = blockIdx.z;
  const int tid = threadIdx.x, lane = tid & 63, w = tid >> 6;
  __shared__ ushort Ks[2][32 * KSTR];   // 2 x 37888 B
  __shared__ ushort Vt[2][512 * 32];    // 2 x 32768 B, [v][key] stride 32
  __shared__ ushort Pl[8][16 * 40];     // 10240 B, per-wave P

  const int fr = lane & 15, g = lane >> 4;

  auto stageK = [&](int kt, int buf) {
    const ushort* ksrc = keff + ((size_t)b * SEQ + (size_t)kt * 32) * KSTR;
    ushort* kd = &Ks[buf][0];
#pragma unroll
    for (int i = 0; i < 5; ++i) {
      int c0 = w * 320 + i * 64;
      if (c0 < KCH) {
        int c = c0 + lane;
        gld_lds16(ksrc + (size_t)c * 8, (void*)(kd + (size_t)c * 8));
      }
    }
  };
  auto stageV = [&](int kt, int buf) {
    const ushort* vsrc = kvT + (size_t)b * 512 * SEQ + (size_t)kt * 32;
    ushort* vd = &Vt[buf][0];
#pragma unroll
    for (int i = 0; i < 4; ++i) {
      int c = w * 256 + i * 64 + lane;
      gld_lds16(vsrc + (size_t)(c >> 2) * SEQ + (c & 3) * 8, (void*)(vd + (size_t)c * 8));
    }
  };

  for (int half = 0; half < 2; ++half) {
    const int qb = half ? pair : (15 - pair);
    const int q0 = qb * 128 + w * 16;   // wave's first q row (in batch)

    const ushort* qrow = q_eff + ((size_t)h * T_TOK + (size_t)b * SEQ + q0 + fr) * DQK + g * 8;
    short8 qf[18];
#pragma unroll
    for (int ks = 0; ks < 18; ++ks) qf[ks] = *(const short8*)(qrow + ks * 32);

    f32x4 acc[32] = {};
    float m_s[4] = {-1e30f, -1e30f, -1e30f, -1e30f};
    float l_s[4] = {0.f, 0.f, 0.f, 0.f};

    const int nt = 4 * qb + 4;

    stageK(0, 0);
    stageV(0, 0);

    for (int kt = 0; kt < nt; ++kt) {
      const int cur = kt & 1;
      if (kt + 1 < nt) {
        stageK(kt + 1, cur ^ 1);
        stageV(kt + 1, cur ^ 1);
        if (w == 7) asm volatile("s_waitcnt vmcnt(6)" ::: "memory");
        else        asm volatile("s_waitcnt vmcnt(9)" ::: "memory");
      } else {
        asm volatile("s_waitcnt vmcnt(0)" ::: "memory");
      }
      __builtin_amdgcn_sched_barrier(0);
      __builtin_amdgcn_s_barrier();
      __builtin_amdgcn_sched_barrier(0);

      if (kt * 32 <= q0 + 15) {
        const ushort* Kc = &Ks[cur][0];
        const ushort* Vc = &Vt[cur][0];
        f32x4 s0 = {}, s1 = {};
        __builtin_amdgcn_s_setprio(1);
#pragma unroll
        for (int ks = 0; ks < 18; ++ks) {
          short8 b0 = *(const short8*)(Kc + (0 * 16 + fr) * KSTR + ks * 32 + g * 8);
          short8 b1 = *(const short8*)(Kc + (1 * 16 + fr) * KSTR + ks * 32 + g * 8);
          s0 = __builtin_amdgcn_mfma_f32_16x16x32_bf16(qf[ks], b0, s0, 0, 0, 0);
          s1 = __builtin_amdgcn_mfma_f32_16x16x32_bf16(qf[ks], b1, s1, 0, 0, 0);
        }
        __builtin_amdgcn_s_setprio(0);
        const float SC = 0.07216878364870322f;   // 1/sqrt(DN+DR=192)
        const bool diag = (kt * 32 + 31 > q0);
        float sv0[4], sv1[4];
#pragma unroll
        for (int r = 0; r < 4; ++r) {
          int qg = q0 + 4 * g + r;
          float a0 = s0[r] * SC, a1 = s1[r] * SC;
          if (diag) {
            if (kt * 32 + fr > qg)      a0 = -1e30f;
            if (kt * 32 + 16 + fr > qg) a1 = -1e30f;
          }
          sv0[r] = a0; sv1[r] = a1;
        }
        float mx[4];
#pragma unroll
        for (int r = 0; r < 4; ++r) {
          float m2 = fmaxf(sv0[r], sv1[r]);
          m2 = fmaxf(m2, __shfl_xor(m2, 1));
          m2 = fmaxf(m2, __shfl_xor(m2, 2));
          m2 = fmaxf(m2, __shfl_xor(m2, 4));
          m2 = fmaxf(m2, __shfl_xor(m2, 8));
          mx[r] = m2;
        }
        float need = mx[0] - m_s[0];
#pragma unroll
        for (int r = 1; r < 4; ++r) need = fmaxf(need, mx[r] - m_s[r]);
        if (__any(need > 8.0f)) {
          float rsc[4];
#pragma unroll
          for (int r = 0; r < 4; ++r) {
            float mn = fmaxf(m_s[r], mx[r]);
            rsc[r] = __expf(m_s[r] - mn);
            m_s[r] = mn;
            l_s[r] *= rsc[r];
          }
#pragma unroll
          for (int n2 = 0; n2 < 32; ++n2)
#pragma unroll
            for (int r = 0; r < 4; ++r) acc[n2][r] *= rsc[r];
        }
        float p0[4], p1[4];
#pragma unroll
        for (int r = 0; r < 4; ++r) {
          p0[r] = __expf(sv0[r] - m_s[r]);
          p1[r] = __expf(sv1[r] - m_s[r]);
          float ps = p0[r] + p1[r];
          ps += __shfl_xor(ps, 1);
          ps += __shfl_xor(ps, 2);
          ps += __shfl_xor(ps, 4);
          ps += __shfl_xor(ps, 8);
          l_s[r] += ps;
          Pl[w][(4 * g + r) * 40 + fr]      = f2bf(p0[r]);
          Pl[w][(4 * g + r) * 40 + 16 + fr] = f2bf(p1[r]);
        }
        short8 pa = *(const short8*)(Pl[w] + fr * 40 + g * 8);
        __builtin_amdgcn_s_setprio(1);
#pragma unroll
        for (int n2 = 0; n2 < 32; ++n2) {
          short8 bv = *(const short8*)(Vc + (n2 * 16 + fr) * 32 + g * 8);
          acc[n2] = __builtin_amdgcn_mfma_f32_16x16x32_bf16(pa, bv, acc[n2], 0, 0, 0);
        }
        __builtin_amdgcn_s_setprio(0);
      }
      __builtin_amdgcn_sched_barrier(0);
      __builtin_amdgcn_s_barrier();
      __builtin_amdgcn_sched_barrier(0);
    }

    const size_t obase = ((size_t)h * T_TOK + (size_t)b * SEQ + q0) * LAT;
    float inv[4];
#pragma unroll
    for (int r = 0; r < 4; ++r) inv[r] = 1.0f / l_s[r];
#pragma unroll
    for (int n2 = 0; n2 < 32; ++n2)
#pragma unroll
      for (int r = 0; r < 4; ++r)
        out_lat[obase + (size_t)(4 * g + r) * LAT + n2 * 16 + fr] = f2bf(acc[n2][r] * inv[r]);
  }
}

// ---------------- launch ----------------
extern "C" void kernel_launch(void* const* d_in, const int* in_sizes, int n_in,
                              void* d_out, int out_size, void* d_ws, size_t ws_size,
                              hipStream_t stream) {
  const float* hs   = (const float*)d_in[0];
  const float* cosb = (const float*)d_in[1];
  const float* sinb = (const float*)d_in[2];
  const float* qw   = (const float*)d_in[3];
  const float* kvw  = (const float*)d_in[4];
  const float* lnw  = (const float*)d_in[5];
  const float* wuk  = (const float*)d_in[6];
  const float* wuv  = (const float*)d_in[7];
  const float* wo   = (const float*)d_in[8];
  float* out = (float*)d_out;
  char* ws = (char*)d_ws;

  // workspace layout (bytes); out_lat aliases the region dead by attention time
  const size_t o_xb   = 0;              // 16,777,216
  const size_t o_qb   = 16777216;       // 4096x3712 bf16 = 30,408,704
  const size_t o_wq   = 47185920;       // 12,582,912
  const size_t o_wkv  = 59768832;       // 2,621,440 (contiguous after wq)
  const size_t o_ol   = 0;              // out_lat 67,108,864 (alias; above dead by attn)
  const size_t o_wukt = 67108864;       // 2,097,152
  const size_t o_wuvt = 69206016;       // 2,097,152
  const size_t o_wo   = 71303168;       // 8,388,608
  const size_t o_keff = 79691776;       // 4096x592 bf16 = 4,849,664
  const size_t o_qeff = 84541440;       // 16x4096x576 bf16 = 75,497,472
  const size_t o_oh   = 160038912;      // 16,777,216
  const size_t o_kvt  = 176816128;      // 4,194,304 -> ends 181,010,432

  ushort* xb    = (ushort*)(ws + o_xb);
  ushort* qbuf  = (ushort*)(ws + o_qb);
  ushort* wq_b  = (ushort*)(ws + o_wq);
  ushort* wkv_b = (ushort*)(ws + o_wkv);
  ushort* olat  = (ushort*)(ws + o_ol);
  ushort* wukt  = (ushort*)(ws + o_wukt);
  ushort* wuvt  = (ushort*)(ws + o_wuvt);
  ushort* wo_b  = (ushort*)(ws + o_wo);
  ushort* keff  = (ushort*)(ws + o_keff);
  ushort* qeff  = (ushort*)(ws + o_qeff);
  ushort* ohead = (ushort*)(ws + o_oh);
  ushort* kvt   = (ushort*)(ws + o_kvt);

  // 1) all input casts in one launch
  cast_all<<<27904, 256, 0, stream>>>(hs, qw, kvw, wuk, wuv, wo,
                                      xb, wq_b, wkv_b, wukt, wuvt, wo_b);

  // 2) [q | ckv] = x @ [q_proj_w ; kv_a_proj_w_padded]^T  (bf16 out, merged)
  gemm_bt<1><<<dim3(29, 32, 1), 256, 0, stream>>>(xb, wq_b, qbuf, 2048, 2048, 2048, QCKV, 0, 0, 0);
  // 3) RMSNorm + RoPE-k -> k_eff, and RoPE-q -> q_eff[., 512..576] (fused)
  rms_rope_kq<<<4096, 256, 0, stream>>>(qbuf, lnw, cosb, sinb, keff, qeff);
  // 3b) kvT = kv_c^T per batch
  transpose_kv<<<dim3(32, 8, 2), 256, 0, stream>>>(keff, kvt);
  // 4) q_lat per head -> q_eff[., 0..512]  (K=128 single-stage GEMM)
  gemm_k128<<<dim3(4, 32, 16), 256, 0, stream>>>(qbuf, wukt, qeff, QCKV, 128, 576,
                                                 192LL, 65536LL, 2359296LL);
  // 5) attention -> out_lat
  attn3<<<dim3(8, 16, 2), 512, 0, stream>>>(qeff, keff, kvt, olat);
  // 6) o_head = out_lat @ W_UV (per head)
  gemm_bt<1><<<dim3(1, 32, 16), 256, 0, stream>>>(olat, wuvt, ohead, 512, 512, 512, 2048,
                                                  2097152LL, 65536LL, 128LL);
  // 7) out = o_head @ o_proj_w^T (f32 out)
  gemm_bt<0><<<dim3(16, 32, 1), 256, 0, stream>>>(ohead, wo_b, out, 2048, 2048, 2048, 2048, 0, 0, 0);
}